// Round 1
// baseline (1287.058 us; speedup 1.0000x reference)
//
#include <hip/hip_runtime.h>
#include <hip/hip_bf16.h>
#include <math.h>

#define B_ 2
#define I_ 1024
#define C_ 16
#define H_ 12

__device__ __constant__ float kW_C = 0.23570226039551584f; // sqrt(2/(9*4))
#define W_Lc 0.5773502691896258f
#define LOG2E 1.4426950408889634f

// ws layout (floats):
// qpQ: [B][I][H][32]  (q' 0:16, qp' 16:28, q2'' 28, pad)
// kpK: [B][I][H][56]  (k 0:16, kpts 16:28, vpts 28:52, k2'' 52, m2 53, sinv 54, pad)
// v:   [B][I][H][16]
// acc: [B][I][512]    (opts 0:288 (h,p,x), opair 288:480 (h,c), rowsum 480:492 (h))
#define QPQ_OFF 0
#define QPQ_SZ (B_*I_*H_*32)
#define KPK_OFF (QPQ_OFF + QPQ_SZ)
#define KPK_SZ (B_*I_*H_*56)
#define V_OFF (KPK_OFF + KPK_SZ)
#define V_SZ (B_*I_*H_*16)
#define ACC_OFF (V_OFF + V_SZ)

__global__ __launch_bounds__(192) void kA(const float* __restrict__ s, const float* __restrict__ R,
                 const float* __restrict__ t, const float* __restrict__ Wq,
                 const float* __restrict__ Wk, const float* __restrict__ Wv,
                 const float* __restrict__ Wqp, const float* __restrict__ Wkp,
                 const float* __restrict__ Wvp, const float* __restrict__ gam,
                 float* __restrict__ ws) {
  int blk = blockIdx.x;
  int b = blk >> 10, i = blk & 1023;
  int tid = threadIdx.x;
  __shared__ float sl[16], rl[9], tl[3], part[96];
  if (tid < 16) sl[tid] = s[(b*I_ + i)*C_ + tid];
  else if (tid < 25) rl[tid-16] = R[(size_t)(b*I_+i)*9 + (tid-16)];
  else if (tid < 28) tl[tid-25] = t[(size_t)(b*I_+i)*3 + (tid-25)];
  __syncthreads();
  float* qpQ = ws + QPQ_OFF + (size_t)(b*I_+i)*(H_*32);
  float* kpK = ws + KPK_OFF + (size_t)(b*I_+i)*(H_*56);
  float* vv  = ws + V_OFF  + (size_t)(b*I_+i)*(H_*16);
  // phase 1: q/k/v projections; tid == h*16+c
  {
    int hc = tid; int h = hc >> 4, c = hc & 15;
    float aq = 0.f, ak = 0.f, av = 0.f;
    #pragma unroll
    for (int ci = 0; ci < 16; ci++) {
      float sv = sl[ci];
      aq += sv * Wq[ci*192 + hc];
      ak += sv * Wk[ci*192 + hc];
      av += sv * Wv[ci*192 + hc];
    }
    const float s_qk = 0.25f * W_Lc * LOG2E;
    qpQ[h*32 + c] = aq * s_qk;
    kpK[h*56 + c] = ak;
    vv[hc] = av;
  }
  // phase 2: points (48 qp, 48 kp, 96 vp tasks)
  {
    float raw[3], px[3];
    if (tid < 96) {
      bool isq = tid < 48;
      int n = isq ? tid : tid - 48;
      const float* W = isq ? Wqp : Wkp;
      #pragma unroll
      for (int x = 0; x < 3; x++) {
        float a2 = 0.f;
        #pragma unroll
        for (int ci = 0; ci < 16; ci++) a2 += sl[ci] * W[ci*144 + n*3 + x];
        raw[x] = a2;
      }
      #pragma unroll
      for (int x = 0; x < 3; x++)
        px[x] = rl[x*3]*raw[0] + rl[x*3+1]*raw[1] + rl[x*3+2]*raw[2] + tl[x];
      int h = n >> 2, p = n & 3;
      part[tid] = px[0]*px[0] + px[1]*px[1] + px[2]*px[2];
      if (isq) {
        float g = gam[h];
        float sp = log1pf(expf(g));
        float coef2 = -0.5f * kW_C * sp * W_Lc * LOG2E;
        #pragma unroll
        for (int x = 0; x < 3; x++) qpQ[h*32 + 16 + p*3 + x] = px[x] * (-2.0f * coef2);
      } else {
        #pragma unroll
        for (int x = 0; x < 3; x++) kpK[h*56 + 16 + p*3 + x] = px[x];
      }
    } else {
      int n = tid - 96;
      #pragma unroll
      for (int x = 0; x < 3; x++) {
        float a2 = 0.f;
        #pragma unroll
        for (int ci = 0; ci < 16; ci++) a2 += sl[ci] * Wvp[ci*288 + n*3 + x];
        raw[x] = a2;
      }
      #pragma unroll
      for (int x = 0; x < 3; x++)
        px[x] = rl[x*3]*raw[0] + rl[x*3+1]*raw[1] + rl[x*3+2]*raw[2] + tl[x];
      int h = n >> 3, p = n & 7;
      #pragma unroll
      for (int x = 0; x < 3; x++) kpK[h*56 + 28 + p*3 + x] = px[x];
    }
  }
  __syncthreads();
  if (tid < 24) {
    int h = tid % 12; bool isq = tid < 12;
    float g = gam[h];
    float sp = log1pf(expf(g));
    float coef2 = -0.5f * kW_C * sp * W_Lc * LOG2E;
    float s2 = 0.f;
    int base = isq ? h*4 : 48 + h*4;
    #pragma unroll
    for (int p = 0; p < 4; p++) s2 += part[base + p];
    if (isq) qpQ[h*32 + 28] = coef2 * s2;
    else     kpK[h*56 + 52] = coef2 * s2;
  }
}

// Pass 1: per-(b,h,j) online max & sumexp over i. Block owns 16 j, 192 thr = (h,jl).
__global__ __launch_bounds__(192) void kB(const float* __restrict__ z, const float* __restrict__ Wb,
                 float* __restrict__ ws) {
  int blk = blockIdx.x;
  int b = blk >> 6; int j0 = (blk & 63) << 4;
  int tid = threadIdx.x;
  int jl = tid & 15, h = tid >> 4;
  int j = j0 + jl;
  const float* qpQ = ws + QPQ_OFF;
  float* kpK = ws + KPK_OFF;
  __shared__ float zt[16*132];
  __shared__ float qt[8*384];
  float kr[16], kp[12], k2, wb[16];
  {
    const float* kb = kpK + (size_t)((b*I_+j)*H_ + h)*56;
    #pragma unroll
    for (int c = 0; c < 16; c++) kr[c] = kb[c];
    #pragma unroll
    for (int x = 0; x < 12; x++) kp[x] = kb[16+x];
    k2 = kb[52];
  }
  #pragma unroll
  for (int c = 0; c < 16; c++) wb[c] = Wb[c*12 + h] * (W_Lc * LOG2E);
  float m = -1e30f, S = 0.f;
  for (int ic0 = 0; ic0 < I_; ic0 += 8) {
    __syncthreads();
    {
      const float4* src = (const float4*)(qpQ + (size_t)(b*I_ + ic0)*384);
      float4* dst = (float4*)qt;
      for (int idx = tid; idx < 768; idx += 192) dst[idx] = src[idx];
    }
    for (int idx = tid; idx < 512; idx += 192) {
      int r = idx >> 6, rem = idx & 63;   // 64 float4 per i-row (16j x 16c)
      int jj = rem >> 2, c4 = rem & 3;
      const float4* src = (const float4*)(z + ((size_t)(b*I_ + ic0 + r)*I_ + j0)*C_);
      *((float4*)(zt + jj*132 + r*16 + c4*4)) = src[rem];
    }
    __syncthreads();
    #pragma unroll 1
    for (int il = 0; il < 8; il++) {
      const float* q = qt + il*384 + h*32;
      const float* zr = zt + jl*132 + il*16;
      float l2 = q[28] + k2;
      #pragma unroll
      for (int c = 0; c < 16; c++) l2 += q[c] * kr[c];
      #pragma unroll
      for (int x = 0; x < 12; x++) l2 += q[16+x] * kp[x];
      #pragma unroll
      for (int c = 0; c < 16; c++) l2 += zr[c] * wb[c];
      float mn = fmaxf(m, l2);
      S = S * __builtin_amdgcn_exp2f(m - mn) + __builtin_amdgcn_exp2f(l2 - mn);
      m = mn;
    }
  }
  float* kb = kpK + (size_t)((b*I_+j)*H_ + h)*56;
  kb[53] = m;
  kb[54] = 1.0f / S;
}

// Pass 2: block owns 16 i, 192 thr = (h,il); stream j, accumulate opts/opair/rowsum.
__global__ __launch_bounds__(192) void kC(const float* __restrict__ z, const float* __restrict__ Wb,
                 float* __restrict__ ws) {
  int blk = blockIdx.x;
  int b = blk >> 6; int i0 = (blk & 63) << 4;
  int tid = threadIdx.x;
  int il = tid & 15, h = tid >> 4;
  int i = i0 + il;
  const float* qpQ = ws + QPQ_OFF;
  const float* kpK = ws + KPK_OFF;
  float* acc = ws + ACC_OFF;
  __shared__ float zt[16*132];
  __shared__ float kt[5376];
  float qr[16], qp[12], q2, wb[16];
  {
    const float* qb = qpQ + (size_t)((b*I_+i)*H_ + h)*32;
    #pragma unroll
    for (int c = 0; c < 16; c++) qr[c] = qb[c];
    #pragma unroll
    for (int x = 0; x < 12; x++) qp[x] = qb[16+x];
    q2 = qb[28];
  }
  #pragma unroll
  for (int c = 0; c < 16; c++) wb[c] = Wb[c*12 + h] * (W_Lc * LOG2E);
  float opts[24], opair[16], rsum = 0.f;
  #pragma unroll
  for (int n = 0; n < 24; n++) opts[n] = 0.f;
  #pragma unroll
  for (int c = 0; c < 16; c++) opair[c] = 0.f;
  for (int jc0 = 0; jc0 < I_; jc0 += 8) {
    __syncthreads();
    for (int idx = tid; idx < 512; idx += 192) {   // 16 i-rows x 32 float4 (8j x 16c)
      int r = idx >> 5, q4 = idx & 31;
      const float4* src = (const float4*)(z + ((size_t)(b*I_ + i0 + r)*I_ + jc0)*C_);
      *((float4*)(zt + r*132 + q4*4)) = src[q4];
    }
    {
      const float4* src = (const float4*)(kpK + (size_t)(b*I_ + jc0)*672);
      float4* dst = (float4*)kt;
      for (int idx = tid; idx < 1344; idx += 192) dst[idx] = src[idx];
    }
    __syncthreads();
    #pragma unroll 1
    for (int jj = 0; jj < 8; jj++) {
      const float* kb = kt + jj*672 + h*56;
      const float* zr = zt + il*132 + jj*16;
      float l2 = q2 + kb[52];
      #pragma unroll
      for (int c = 0; c < 16; c++) l2 += qr[c] * kb[c];
      #pragma unroll
      for (int x = 0; x < 12; x++) l2 += qp[x] * kb[16+x];
      float zv[16];
      #pragma unroll
      for (int c = 0; c < 16; c++) { zv[c] = zr[c]; l2 += zv[c] * wb[c]; }
      float w = __builtin_amdgcn_exp2f(l2 - kb[53]) * kb[54];
      rsum += w;
      #pragma unroll
      for (int c = 0; c < 16; c++) opair[c] += w * zv[c];
      #pragma unroll
      for (int n = 0; n < 24; n++) opts[n] += w * kb[28+n];
    }
  }
  float* ab = acc + (size_t)(b*I_+i)*512;
  #pragma unroll
  for (int n = 0; n < 24; n++) ab[h*24 + n] = opts[n];
  #pragma unroll
  for (int c = 0; c < 16; c++) ab[288 + h*16 + c] = opair[c];
  ab[480 + h] = rsum;
}

// Epilogue: build cat[16][768] in LDS, then out = cat @ Wout + bout.
__global__ __launch_bounds__(256) void kD(const float* __restrict__ Wout, const float* __restrict__ bout,
                 const float* __restrict__ ws, float* __restrict__ out) {
  int blk = blockIdx.x;
  int b = blk >> 6; int i0 = (blk & 63) << 4;
  int tid = threadIdx.x;
  __shared__ float cat[16*776];
  const float* acc = ws + ACC_OFF;
  const float* vv = ws + V_OFF;
  for (int idx = tid; idx < 16*768; idx += 256) {
    int r = idx / 768, f = idx - r*768;
    int i = i0 + r;
    const float* ab = acc + (size_t)(b*I_+i)*512;
    float val;
    if (f < 192) {
      int h = f >> 4, c = f & 15;
      val = vv[(size_t)((b*I_+i)*H_ + h)*16 + c] * ab[480 + h];
    } else if (f < 384) {
      val = ab[288 + (f - 192)];
    } else if (f < 672) {
      val = ab[f - 384];
    } else {
      int g = f - 672; int base = (g >> 3)*24 + (g & 7)*3;
      float x0 = ab[base], x1 = ab[base+1], x2 = ab[base+2];
      val = sqrtf(fmaxf(x0*x0 + x1*x1 + x2*x2, 1e-12f));
    }
    cat[r*776 + f] = val;
  }
  __syncthreads();
  int r = tid >> 4, c = tid & 15;
  float sum = bout[c];
  const float* cr = cat + r*776;
  for (int f = 0; f < 768; f++) sum += cr[f] * Wout[f*16 + c];
  out[((size_t)(b*I_) + i0 + r)*16 + c] = sum;
}

extern "C" void kernel_launch(void* const* d_in, const int* in_sizes, int n_in,
                              void* d_out, int out_size, void* d_ws, size_t ws_size,
                              hipStream_t stream) {
  const float* s    = (const float*)d_in[0];
  const float* z    = (const float*)d_in[1];
  const float* R    = (const float*)d_in[2];
  const float* t    = (const float*)d_in[3];
  const float* Wq   = (const float*)d_in[4];
  const float* Wk   = (const float*)d_in[5];
  const float* Wv   = (const float*)d_in[6];
  const float* Wb   = (const float*)d_in[7];
  const float* Wqp  = (const float*)d_in[8];
  const float* Wkp  = (const float*)d_in[9];
  const float* Wvp  = (const float*)d_in[10];
  const float* gam  = (const float*)d_in[11];
  const float* Wout = (const float*)d_in[12];
  const float* bout = (const float*)d_in[13];
  float* out = (float*)d_out;
  float* ws = (float*)d_ws;

  hipLaunchKernelGGL(kA, dim3(B_*I_), dim3(192), 0, stream,
                     s, R, t, Wq, Wk, Wv, Wqp, Wkp, Wvp, gam, ws);
  hipLaunchKernelGGL(kB, dim3(B_*(I_/16)), dim3(192), 0, stream, z, Wb, ws);
  hipLaunchKernelGGL(kC, dim3(B_*(I_/16)), dim3(192), 0, stream, z, Wb, ws);
  hipLaunchKernelGGL(kD, dim3(B_*(I_/16)), dim3(256), 0, stream, Wout, bout, ws, out);
}

// Round 2
// 594.617 us; speedup vs baseline: 2.1645x; 2.1645x over previous
//
#include <hip/hip_runtime.h>
#include <hip/hip_bf16.h>
#include <math.h>

#define B_ 2
#define I_ 1024
#define C_ 16
#define H_ 12
#define ICH 16

__device__ __constant__ float kW_C = 0.23570226039551584f; // sqrt(2/(9*4))
#define W_Lc 0.5773502691896258f
#define LOG2E 1.4426950408889634f

// ws layout (floats):
// qpQ: [B][I][H][32]  (q' 0:16, qp' 16:28, q2'' 28, pad)
// kpK: [B][I][H][56]  (k 0:16, kpts 16:28, vpts 28:52, k2'' 52, m2 53, sinv 54, pad)
// v:   [B][I][H][16]
// pm:  [B][64][ICH][192] float2 partial (m,S)
// acc2:[B][I][jch][512] partial (opts 0:288 (h,p,x), opair 288:480 (h,c), rowsum 480:492 (h))
#define QPQ_OFF 0
#define QPQ_SZ (B_*I_*H_*32)
#define KPK_OFF (QPQ_OFF + QPQ_SZ)
#define KPK_SZ (B_*I_*H_*56)
#define V_OFF (KPK_OFF + KPK_SZ)
#define V_SZ (B_*I_*H_*16)
#define PM_OFF (V_OFF + V_SZ)
#define PM_SZ (B_*64*ICH*192*2)
#define ACC2_OFF (PM_OFF + PM_SZ)

__global__ __launch_bounds__(192) void kA(const float* __restrict__ s, const float* __restrict__ R,
                 const float* __restrict__ t, const float* __restrict__ Wq,
                 const float* __restrict__ Wk, const float* __restrict__ Wv,
                 const float* __restrict__ Wqp, const float* __restrict__ Wkp,
                 const float* __restrict__ Wvp, const float* __restrict__ gam,
                 float* __restrict__ ws) {
  int blk = blockIdx.x;
  int b = blk >> 10, i = blk & 1023;
  int tid = threadIdx.x;
  __shared__ float sl[16], rl[9], tl[3], part[96];
  if (tid < 16) sl[tid] = s[(b*I_ + i)*C_ + tid];
  else if (tid < 25) rl[tid-16] = R[(size_t)(b*I_+i)*9 + (tid-16)];
  else if (tid < 28) tl[tid-25] = t[(size_t)(b*I_+i)*3 + (tid-25)];
  __syncthreads();
  float* qpQ = ws + QPQ_OFF + (size_t)(b*I_+i)*(H_*32);
  float* kpK = ws + KPK_OFF + (size_t)(b*I_+i)*(H_*56);
  float* vv  = ws + V_OFF  + (size_t)(b*I_+i)*(H_*16);
  // phase 1: q/k/v projections; tid == h*16+c
  {
    int hc = tid; int h = hc >> 4, c = hc & 15;
    float aq = 0.f, ak = 0.f, av = 0.f;
    #pragma unroll
    for (int ci = 0; ci < 16; ci++) {
      float sv = sl[ci];
      aq += sv * Wq[ci*192 + hc];
      ak += sv * Wk[ci*192 + hc];
      av += sv * Wv[ci*192 + hc];
    }
    const float s_qk = 0.25f * W_Lc * LOG2E;
    qpQ[h*32 + c] = aq * s_qk;
    kpK[h*56 + c] = ak;
    vv[hc] = av;
  }
  // phase 2: points (48 qp, 48 kp, 96 vp tasks)
  {
    float raw[3], px[3];
    if (tid < 96) {
      bool isq = tid < 48;
      int n = isq ? tid : tid - 48;
      const float* W = isq ? Wqp : Wkp;
      #pragma unroll
      for (int x = 0; x < 3; x++) {
        float a2 = 0.f;
        #pragma unroll
        for (int ci = 0; ci < 16; ci++) a2 += sl[ci] * W[ci*144 + n*3 + x];
        raw[x] = a2;
      }
      #pragma unroll
      for (int x = 0; x < 3; x++)
        px[x] = rl[x*3]*raw[0] + rl[x*3+1]*raw[1] + rl[x*3+2]*raw[2] + tl[x];
      int h = n >> 2, p = n & 3;
      part[tid] = px[0]*px[0] + px[1]*px[1] + px[2]*px[2];
      if (isq) {
        float g = gam[h];
        float sp = log1pf(expf(g));
        float coef2 = -0.5f * kW_C * sp * W_Lc * LOG2E;
        #pragma unroll
        for (int x = 0; x < 3; x++) qpQ[h*32 + 16 + p*3 + x] = px[x] * (-2.0f * coef2);
      } else {
        #pragma unroll
        for (int x = 0; x < 3; x++) kpK[h*56 + 16 + p*3 + x] = px[x];
      }
    } else {
      int n = tid - 96;
      #pragma unroll
      for (int x = 0; x < 3; x++) {
        float a2 = 0.f;
        #pragma unroll
        for (int ci = 0; ci < 16; ci++) a2 += sl[ci] * Wvp[ci*288 + n*3 + x];
        raw[x] = a2;
      }
      #pragma unroll
      for (int x = 0; x < 3; x++)
        px[x] = rl[x*3]*raw[0] + rl[x*3+1]*raw[1] + rl[x*3+2]*raw[2] + tl[x];
      int h = n >> 3, p = n & 7;
      #pragma unroll
      for (int x = 0; x < 3; x++) kpK[h*56 + 28 + p*3 + x] = px[x];
    }
  }
  __syncthreads();
  if (tid < 24) {
    int h = tid % 12; bool isq = tid < 12;
    float g = gam[h];
    float sp = log1pf(expf(g));
    float coef2 = -0.5f * kW_C * sp * W_Lc * LOG2E;
    float s2 = 0.f;
    int base = isq ? h*4 : 48 + h*4;
    #pragma unroll
    for (int p = 0; p < 4; p++) s2 += part[base + p];
    if (isq) qpQ[h*32 + 28] = coef2 * s2;
    else     kpK[h*56 + 52] = coef2 * s2;
  }
}

// Pass 1 (partial): block owns 16 j (jt) and an i-chunk of 64 (ic). thr=(h,jl).
// No LDS: q-side rows broadcast from L1/L2, z coalesced from HBM.
__global__ __launch_bounds__(192,3) void kB(const float* __restrict__ z,
                 const float* __restrict__ Wb, float* __restrict__ ws) {
  int blk = blockIdx.x;
  int ic = blk & 15; int jt = (blk >> 4) & 63; int b = blk >> 10;
  int tid = threadIdx.x; int h = tid >> 4, jl = tid & 15;
  int j = jt*16 + jl;
  const float* qpQ = ws + QPQ_OFF;
  const float* kpK = ws + KPK_OFF;
  const float4* kb4 = (const float4*)(kpK + ((size_t)(b*I_+j)*H_ + h)*56);
  float4 ka = kb4[0], kb_ = kb4[1], kc = kb4[2], kd = kb4[3];
  float4 kpa = kb4[4], kpb = kb4[5], kpc = kb4[6];
  float k2 = kb4[13].x;
  float wb[16];
  #pragma unroll
  for (int c = 0; c < 16; c++) wb[c] = Wb[c*12 + h] * (W_Lc * LOG2E);
  float m = -1e30f, S = 0.f;
  int i0 = ic*64;
  const float4* qrow = (const float4*)(qpQ + ((size_t)(b*I_+i0)*H_ + h)*32);
  const float4* zrow = (const float4*)(z + ((size_t)(b*I_+i0)*I_ + j)*16);
  for (int ii = 0; ii < 64; ii++) {
    float4 qa = qrow[0], qb = qrow[1], qc = qrow[2], qd = qrow[3];
    float4 qpa = qrow[4], qpb = qrow[5], qpc = qrow[6];
    float q2 = qrow[7].x;
    float4 z0 = zrow[0], z1 = zrow[1], z2 = zrow[2], z3 = zrow[3];
    float s0 = qa.x*ka.x + qa.y*ka.y + qa.z*ka.z + qa.w*ka.w
             + qpa.x*kpa.x + qpa.y*kpa.y + qpa.z*kpa.z + qpa.w*kpa.w
             + z0.x*wb[0] + z0.y*wb[1] + z0.z*wb[2] + z0.w*wb[3];
    float s1 = qb.x*kb_.x + qb.y*kb_.y + qb.z*kb_.z + qb.w*kb_.w
             + qpb.x*kpb.x + qpb.y*kpb.y + qpb.z*kpb.z + qpb.w*kpb.w
             + z1.x*wb[4] + z1.y*wb[5] + z1.z*wb[6] + z1.w*wb[7];
    float s2 = qc.x*kc.x + qc.y*kc.y + qc.z*kc.z + qc.w*kc.w
             + qpc.x*kpc.x + qpc.y*kpc.y + qpc.z*kpc.z + qpc.w*kpc.w
             + z2.x*wb[8] + z2.y*wb[9] + z2.z*wb[10] + z2.w*wb[11];
    float s3 = qd.x*kd.x + qd.y*kd.y + qd.z*kd.z + qd.w*kd.w
             + z3.x*wb[12] + z3.y*wb[13] + z3.z*wb[14] + z3.w*wb[15]
             + q2 + k2;
    float l2 = (s0 + s1) + (s2 + s3);
    float mn = fmaxf(m, l2);
    S = S * __builtin_amdgcn_exp2f(m - mn) + __builtin_amdgcn_exp2f(l2 - mn);
    m = mn;
    qrow += 96; zrow += 4096;
  }
  float2* pm = (float2*)(ws + PM_OFF);
  pm[((size_t)(b*64+jt)*ICH + ic)*192 + tid] = make_float2(m, S);
}

// merge ICH partial (m,S) -> kpK[53]=m, [54]=1/S
__global__ __launch_bounds__(192) void kB2(float* __restrict__ ws) {
  int blk = blockIdx.x; int jt = blk & 63, b = blk >> 6;
  int tid = threadIdx.x; int h = tid >> 4, jl = tid & 15;
  const float2* pm = (const float2*)(ws + PM_OFF) + (size_t)(b*64+jt)*ICH*192 + tid;
  float m = -1e30f, S = 0.f;
  #pragma unroll
  for (int ic = 0; ic < ICH; ic++) {
    float2 p = pm[ic*192];
    float mn = fmaxf(m, p.x);
    S = S * __builtin_amdgcn_exp2f(m - mn) + p.y * __builtin_amdgcn_exp2f(p.x - mn);
    m = mn;
  }
  int j = jt*16 + jl;
  float* kb = ws + KPK_OFF + ((size_t)(b*I_+j)*H_ + h)*56;
  kb[53] = m;
  kb[54] = 1.0f / S;
}

// Pass 2 (partial): block owns 16 i (it) and a j-chunk (jc of jch). thr=(h,il).
// No LDS: k-side rows from L1/L2 per j, z direct.
__global__ __launch_bounds__(192,3) void kC(const float* __restrict__ z,
                 const float* __restrict__ Wb, float* __restrict__ ws, int jsh) {
  int blk = blockIdx.x;
  int jch = 1 << jsh;
  int jc = blk & (jch-1); int it = (blk >> jsh) & 63; int b = blk >> (jsh+6);
  int tid = threadIdx.x; int h = tid >> 4, il = tid & 15;
  int i = it*16 + il;
  const float* qpQ = ws + QPQ_OFF;
  const float* kpK = ws + KPK_OFF;
  const float4* q4 = (const float4*)(qpQ + ((size_t)(b*I_+i)*H_ + h)*32);
  float4 qa = q4[0], qb = q4[1], qc = q4[2], qd = q4[3];
  float4 qpa = q4[4], qpb = q4[5], qpc = q4[6];
  float q2 = q4[7].x;
  float wb[16];
  #pragma unroll
  for (int c = 0; c < 16; c++) wb[c] = Wb[c*12 + h] * (W_Lc * LOG2E);
  float opts[24], opair[16], rsum = 0.f;
  #pragma unroll
  for (int n = 0; n < 24; n++) opts[n] = 0.f;
  #pragma unroll
  for (int c = 0; c < 16; c++) opair[c] = 0.f;
  int chunk = I_ >> jsh;
  int j0 = jc * chunk;
  const float4* zrow = (const float4*)(z + ((size_t)(b*I_+i)*I_ + j0)*16);
  const float4* krow = (const float4*)(kpK + ((size_t)(b*I_+j0)*H_ + h)*56);
  for (int jj = 0; jj < chunk; jj++) {
    float4 k0 = krow[0], k1 = krow[1], k2v = krow[2], k3 = krow[3];
    float4 kp0 = krow[4], kp1 = krow[5], kp2 = krow[6];
    float4 tl = krow[13];
    float4 z0 = zrow[0], z1 = zrow[1], z2 = zrow[2], z3 = zrow[3];
    float s0 = qa.x*k0.x + qa.y*k0.y + qa.z*k0.z + qa.w*k0.w
             + qpa.x*kp0.x + qpa.y*kp0.y + qpa.z*kp0.z + qpa.w*kp0.w
             + z0.x*wb[0] + z0.y*wb[1] + z0.z*wb[2] + z0.w*wb[3];
    float s1 = qb.x*k1.x + qb.y*k1.y + qb.z*k1.z + qb.w*k1.w
             + qpb.x*kp1.x + qpb.y*kp1.y + qpb.z*kp1.z + qpb.w*kp1.w
             + z1.x*wb[4] + z1.y*wb[5] + z1.z*wb[6] + z1.w*wb[7];
    float s2 = qc.x*k2v.x + qc.y*k2v.y + qc.z*k2v.z + qc.w*k2v.w
             + qpc.x*kp2.x + qpc.y*kp2.y + qpc.z*kp2.z + qpc.w*kp2.w
             + z2.x*wb[8] + z2.y*wb[9] + z2.z*wb[10] + z2.w*wb[11];
    float s3 = qd.x*k3.x + qd.y*k3.y + qd.z*k3.z + qd.w*k3.w
             + z3.x*wb[12] + z3.y*wb[13] + z3.z*wb[14] + z3.w*wb[15]
             + q2 + tl.x;
    float l2 = (s0 + s1) + (s2 + s3);
    float w = __builtin_amdgcn_exp2f(l2 - tl.y) * tl.z;
    rsum += w;
    opair[0] += w*z0.x; opair[1] += w*z0.y; opair[2] += w*z0.z; opair[3] += w*z0.w;
    opair[4] += w*z1.x; opair[5] += w*z1.y; opair[6] += w*z1.z; opair[7] += w*z1.w;
    opair[8] += w*z2.x; opair[9] += w*z2.y; opair[10] += w*z2.z; opair[11] += w*z2.w;
    opair[12] += w*z3.x; opair[13] += w*z3.y; opair[14] += w*z3.z; opair[15] += w*z3.w;
    float4 v0 = krow[7], v1 = krow[8];
    opts[0] += w*v0.x; opts[1] += w*v0.y; opts[2] += w*v0.z; opts[3] += w*v0.w;
    opts[4] += w*v1.x; opts[5] += w*v1.y; opts[6] += w*v1.z; opts[7] += w*v1.w;
    float4 v2 = krow[9], v3 = krow[10];
    opts[8] += w*v2.x; opts[9] += w*v2.y; opts[10] += w*v2.z; opts[11] += w*v2.w;
    opts[12] += w*v3.x; opts[13] += w*v3.y; opts[14] += w*v3.z; opts[15] += w*v3.w;
    float4 v4 = krow[11], v5 = krow[12];
    opts[16] += w*v4.x; opts[17] += w*v4.y; opts[18] += w*v4.z; opts[19] += w*v4.w;
    opts[20] += w*v5.x; opts[21] += w*v5.y; opts[22] += w*v5.z; opts[23] += w*v5.w;
    zrow += 4; krow += 168;
  }
  float* ab = ws + ACC2_OFF + ((size_t)(b*I_+i)*jch + jc)*512;
  #pragma unroll
  for (int n = 0; n < 24; n++) ab[h*24 + n] = opts[n];
  #pragma unroll
  for (int c = 0; c < 16; c++) ab[288 + h*16 + c] = opair[c];
  ab[480 + h] = rsum;
}

// Epilogue: reduce jch partials, build cat[8][768], out = cat @ Wout + bout.
__global__ __launch_bounds__(256) void kD(const float* __restrict__ Wout, const float* __restrict__ bout,
                 const float* __restrict__ ws, float* __restrict__ out, int jsh) {
  int jch = 1 << jsh;
  int blk = blockIdx.x;
  int b = blk >> 7; int i0 = (blk & 127) << 3;
  int tid = threadIdx.x;
  __shared__ float accs[8*512];
  __shared__ float cat[8*776];
  const float* acc2 = ws + ACC2_OFF;
  for (int idx = tid; idx < 8*512; idx += 256) {
    int r = idx >> 9, f = idx & 511;
    const float* src = acc2 + (size_t)(b*I_+i0+r)*jch*512 + f;
    float ssum = 0.f;
    for (int jc = 0; jc < jch; jc++) ssum += src[jc*512];
    accs[idx] = ssum;
  }
  __syncthreads();
  const float* vv = ws + V_OFF;
  for (int idx = tid; idx < 8*768; idx += 256) {
    int r = idx / 768, f = idx - r*768;
    int i = i0 + r;
    const float* ab = accs + r*512;
    float val;
    if (f < 192) {
      int h = f >> 4, c = f & 15;
      val = vv[((size_t)(b*I_+i)*H_ + h)*16 + c] * ab[480 + h];
    } else if (f < 384) {
      val = ab[288 + (f - 192)];
    } else if (f < 672) {
      val = ab[f - 384];
    } else {
      int g = f - 672; int base = (g >> 3)*24 + (g & 7)*3;
      float x0 = ab[base], x1 = ab[base+1], x2 = ab[base+2];
      val = sqrtf(fmaxf(x0*x0 + x1*x1 + x2*x2, 1e-12f));
    }
    cat[r*776 + f] = val;
  }
  __syncthreads();
  if (tid < 128) {
    int r = tid >> 4, c = tid & 15;
    float sum = bout[c];
    const float* cr = cat + r*776;
    float a0 = 0.f, a1 = 0.f, a2 = 0.f, a3 = 0.f;
    for (int f = 0; f < 768; f += 4) {
      a0 += cr[f]   * Wout[f*16 + c];
      a1 += cr[f+1] * Wout[(f+1)*16 + c];
      a2 += cr[f+2] * Wout[(f+2)*16 + c];
      a3 += cr[f+3] * Wout[(f+3)*16 + c];
    }
    out[((size_t)(b*I_) + i0 + r)*16 + c] = sum + (a0+a1) + (a2+a3);
  }
}

extern "C" void kernel_launch(void* const* d_in, const int* in_sizes, int n_in,
                              void* d_out, int out_size, void* d_ws, size_t ws_size,
                              hipStream_t stream) {
  const float* s    = (const float*)d_in[0];
  const float* z    = (const float*)d_in[1];
  const float* R    = (const float*)d_in[2];
  const float* t    = (const float*)d_in[3];
  const float* Wq   = (const float*)d_in[4];
  const float* Wk   = (const float*)d_in[5];
  const float* Wv   = (const float*)d_in[6];
  const float* Wb   = (const float*)d_in[7];
  const float* Wqp  = (const float*)d_in[8];
  const float* Wkp  = (const float*)d_in[9];
  const float* Wvp  = (const float*)d_in[10];
  const float* gam  = (const float*)d_in[11];
  const float* Wout = (const float*)d_in[12];
  const float* bout = (const float*)d_in[13];
  float* out = (float*)d_out;
  float* ws = (float*)d_ws;

  // pick largest jch (power of 2, <=8) whose partial buffer fits ws
  int jsh = 3;
  while (jsh > 0) {
    size_t need = ((size_t)ACC2_OFF + (size_t)B_*I_*(1u<<jsh)*512) * 4u;
    if (need <= ws_size) break;
    jsh--;
  }
  int jch = 1 << jsh;

  hipLaunchKernelGGL(kA, dim3(B_*I_), dim3(192), 0, stream,
                     s, R, t, Wq, Wk, Wv, Wqp, Wkp, Wvp, gam, ws);
  hipLaunchKernelGGL(kB, dim3(B_*64*ICH), dim3(192), 0, stream, z, Wb, ws);
  hipLaunchKernelGGL(kB2, dim3(B_*64), dim3(192), 0, stream, ws);
  hipLaunchKernelGGL(kC, dim3(B_*64*jch), dim3(192), 0, stream, z, Wb, ws, jsh);
  hipLaunchKernelGGL(kD, dim3(B_*(I_/8)), dim3(256), 0, stream, Wout, bout, ws, out, jsh);
}

// Round 3
// 430.976 us; speedup vs baseline: 2.9864x; 1.3797x over previous
//
#include <hip/hip_runtime.h>
#include <hip/hip_bf16.h>
#include <math.h>

#define B_ 2
#define I_ 1024
#define C_ 16
#define H_ 12
#define ICH 16

__device__ __constant__ float kW_C = 0.23570226039551584f; // sqrt(2/(9*4))
#define W_Lc 0.5773502691896258f
#define LOG2E 1.4426950408889634f

// ws layout (floats):
// qpQ: [B][I][H][32]  (q' 0:16, qp' 16:28, q2'' 28, pad)
// kpK: [B][I][H][56]  (k 0:16, kpts 16:28, vpts 28:52, k2'' 52, m2 53, sinv 54, pad)
// v:   [B][I][H][16]
// pm:  [B][64][ICH][192] float2 partial (m,S)
// acc2:[B][I][jch][512] partial (opts 0:288 (h,p,x), opair 288:480 (h,c), rowsum 480:492 (h))
#define QPQ_OFF 0
#define QPQ_SZ (B_*I_*H_*32)
#define KPK_OFF (QPQ_OFF + QPQ_SZ)
#define KPK_SZ (B_*I_*H_*56)
#define V_OFF (KPK_OFF + KPK_SZ)
#define V_SZ (B_*I_*H_*16)
#define PM_OFF (V_OFF + V_SZ)
#define PM_SZ (B_*64*ICH*192*2)
#define ACC2_OFF (PM_OFF + PM_SZ)

__global__ __launch_bounds__(192) void kA(const float* __restrict__ s, const float* __restrict__ R,
                 const float* __restrict__ t, const float* __restrict__ Wq,
                 const float* __restrict__ Wk, const float* __restrict__ Wv,
                 const float* __restrict__ Wqp, const float* __restrict__ Wkp,
                 const float* __restrict__ Wvp, const float* __restrict__ gam,
                 float* __restrict__ ws) {
  int blk = blockIdx.x;
  int b = blk >> 10, i = blk & 1023;
  int tid = threadIdx.x;
  __shared__ float sl[16], rl[9], tl[3], part[96];
  if (tid < 16) sl[tid] = s[(b*I_ + i)*C_ + tid];
  else if (tid < 25) rl[tid-16] = R[(size_t)(b*I_+i)*9 + (tid-16)];
  else if (tid < 28) tl[tid-25] = t[(size_t)(b*I_+i)*3 + (tid-25)];
  __syncthreads();
  float* qpQ = ws + QPQ_OFF + (size_t)(b*I_+i)*(H_*32);
  float* kpK = ws + KPK_OFF + (size_t)(b*I_+i)*(H_*56);
  float* vv  = ws + V_OFF  + (size_t)(b*I_+i)*(H_*16);
  // phase 1: q/k/v projections; tid == h*16+c
  {
    int hc = tid; int h = hc >> 4, c = hc & 15;
    float aq = 0.f, ak = 0.f, av = 0.f;
    #pragma unroll
    for (int ci = 0; ci < 16; ci++) {
      float sv = sl[ci];
      aq += sv * Wq[ci*192 + hc];
      ak += sv * Wk[ci*192 + hc];
      av += sv * Wv[ci*192 + hc];
    }
    const float s_qk = 0.25f * W_Lc * LOG2E;
    qpQ[h*32 + c] = aq * s_qk;
    kpK[h*56 + c] = ak;
    vv[hc] = av;
  }
  // phase 2: points (48 qp, 48 kp, 96 vp tasks)
  {
    float raw[3], px[3];
    if (tid < 96) {
      bool isq = tid < 48;
      int n = isq ? tid : tid - 48;
      const float* W = isq ? Wqp : Wkp;
      #pragma unroll
      for (int x = 0; x < 3; x++) {
        float a2 = 0.f;
        #pragma unroll
        for (int ci = 0; ci < 16; ci++) a2 += sl[ci] * W[ci*144 + n*3 + x];
        raw[x] = a2;
      }
      #pragma unroll
      for (int x = 0; x < 3; x++)
        px[x] = rl[x*3]*raw[0] + rl[x*3+1]*raw[1] + rl[x*3+2]*raw[2] + tl[x];
      int h = n >> 2, p = n & 3;
      part[tid] = px[0]*px[0] + px[1]*px[1] + px[2]*px[2];
      if (isq) {
        float g = gam[h];
        float sp = log1pf(expf(g));
        float coef2 = -0.5f * kW_C * sp * W_Lc * LOG2E;
        #pragma unroll
        for (int x = 0; x < 3; x++) qpQ[h*32 + 16 + p*3 + x] = px[x] * (-2.0f * coef2);
      } else {
        #pragma unroll
        for (int x = 0; x < 3; x++) kpK[h*56 + 16 + p*3 + x] = px[x];
      }
    } else {
      int n = tid - 96;
      #pragma unroll
      for (int x = 0; x < 3; x++) {
        float a2 = 0.f;
        #pragma unroll
        for (int ci = 0; ci < 16; ci++) a2 += sl[ci] * Wvp[ci*288 + n*3 + x];
        raw[x] = a2;
      }
      #pragma unroll
      for (int x = 0; x < 3; x++)
        px[x] = rl[x*3]*raw[0] + rl[x*3+1]*raw[1] + rl[x*3+2]*raw[2] + tl[x];
      int h = n >> 3, p = n & 7;
      #pragma unroll
      for (int x = 0; x < 3; x++) kpK[h*56 + 28 + p*3 + x] = px[x];
    }
  }
  __syncthreads();
  if (tid < 24) {
    int h = tid % 12; bool isq = tid < 12;
    float g = gam[h];
    float sp = log1pf(expf(g));
    float coef2 = -0.5f * kW_C * sp * W_Lc * LOG2E;
    float s2 = 0.f;
    int base = isq ? h*4 : 48 + h*4;
    #pragma unroll
    for (int p = 0; p < 4; p++) s2 += part[base + p];
    if (isq) qpQ[h*32 + 28] = coef2 * s2;
    else     kpK[h*56 + 52] = coef2 * s2;
  }
}

// Pass 1 (partial): block owns 16 j (jt) and an i-chunk of 64 (ic). thr=(h,jl).
// z staged per 16-i tile in LDS (coalesced); q-side direct (L1 broadcast).
__global__ __launch_bounds__(192,4) void kB(const float* __restrict__ z,
                 const float* __restrict__ Wb, float* __restrict__ ws) {
  int blk = blockIdx.x;
  int ic = blk & (ICH-1); int jt = (blk >> 4) & 63; int b = blk >> 10;
  int tid = threadIdx.x; int h = tid >> 4, jl = tid & 15;
  int j0 = jt*16;
  int j = j0 + jl;
  const float* qpQ = ws + QPQ_OFF;
  float* kpK = ws + KPK_OFF;
  __shared__ float4 zt4[16*81];   // [i 16][j 16 stride 5][c4 4] (pad slot 5th)
  const float4* kb4 = (const float4*)(kpK + ((size_t)(b*I_+j)*H_ + h)*56);
  float4 ka = kb4[0], kb_ = kb4[1], kc = kb4[2], kd = kb4[3];
  float4 kpa = kb4[4], kpb = kb4[5], kpc = kb4[6];
  float k2 = kb4[13].x;
  float wb[16];
  #pragma unroll
  for (int c = 0; c < 16; c++) wb[c] = Wb[c*12 + h] * (W_Lc * LOG2E);
  float m = -1e30f, S = 0.f;
  int ibase = ic*64;
  for (int t = 0; t < 4; ++t) {
    int i0 = ibase + t*16;
    __syncthreads();
    for (int idx = tid; idx < 1024; idx += 192) {
      int r = idx >> 6, rem = idx & 63, jj = rem >> 2, c4 = rem & 3;
      const float4* src = (const float4*)(z + ((size_t)(b*I_ + i0 + r)*I_ + j0 + jj)*16);
      zt4[r*81 + jj*5 + c4] = src[c4];
    }
    __syncthreads();
    #pragma unroll 2
    for (int ii = 0; ii < 16; ++ii) {
      const float4* qrow = (const float4*)(qpQ + ((size_t)(b*I_+i0+ii)*H_ + h)*32);
      float4 qa = qrow[0], qb = qrow[1], qc = qrow[2], qd = qrow[3];
      float4 qpa = qrow[4], qpb = qrow[5], qpc = qrow[6];
      float q2 = qrow[7].x;
      const float4* zr = zt4 + jl*81 + ii*5;   // NOTE: thread's j is jl -> row=ii? see layout below
      // layout is [i][j]; thread needs z[i0+ii][j] -> zt4[ii*81 + jl*5 + c4]
      zr = zt4 + ii*81 + jl*5;
      float4 z0 = zr[0], z1 = zr[1], z2 = zr[2], z3 = zr[3];
      float s0 = qa.x*ka.x + qa.y*ka.y + qa.z*ka.z + qa.w*ka.w
               + qpa.x*kpa.x + qpa.y*kpa.y + qpa.z*kpa.z + qpa.w*kpa.w
               + z0.x*wb[0] + z0.y*wb[1] + z0.z*wb[2] + z0.w*wb[3];
      float s1 = qb.x*kb_.x + qb.y*kb_.y + qb.z*kb_.z + qb.w*kb_.w
               + qpb.x*kpb.x + qpb.y*kpb.y + qpb.z*kpb.z + qpb.w*kpb.w
               + z1.x*wb[4] + z1.y*wb[5] + z1.z*wb[6] + z1.w*wb[7];
      float s2 = qc.x*kc.x + qc.y*kc.y + qc.z*kc.z + qc.w*kc.w
               + qpc.x*kpc.x + qpc.y*kpc.y + qpc.z*kpc.z + qpc.w*kpc.w
               + z2.x*wb[8] + z2.y*wb[9] + z2.z*wb[10] + z2.w*wb[11];
      float s3 = qd.x*kd.x + qd.y*kd.y + qd.z*kd.z + qd.w*kd.w
               + z3.x*wb[12] + z3.y*wb[13] + z3.z*wb[14] + z3.w*wb[15]
               + q2 + k2;
      float l2 = (s0 + s1) + (s2 + s3);
      float mn = fmaxf(m, l2);
      S = S * __builtin_amdgcn_exp2f(m - mn) + __builtin_amdgcn_exp2f(l2 - mn);
      m = mn;
    }
  }
  float2* pm = (float2*)(ws + PM_OFF);
  pm[((size_t)(b*64+jt)*ICH + ic)*192 + tid] = make_float2(m, S);
}

// merge ICH partial (m,S) -> kpK[53]=m, [54]=1/S
__global__ __launch_bounds__(192) void kB2(float* __restrict__ ws) {
  int blk = blockIdx.x; int jt = blk & 63, b = blk >> 6;
  int tid = threadIdx.x; int h = tid >> 4, jl = tid & 15;
  const float2* pm = (const float2*)(ws + PM_OFF) + (size_t)(b*64+jt)*ICH*192 + tid;
  float m = -1e30f, S = 0.f;
  #pragma unroll
  for (int ic = 0; ic < ICH; ic++) {
    float2 p = pm[ic*192];
    float mn = fmaxf(m, p.x);
    S = S * __builtin_amdgcn_exp2f(m - mn) + p.y * __builtin_amdgcn_exp2f(p.x - mn);
    m = mn;
  }
  int j = jt*16 + jl;
  float* kb = ws + KPK_OFF + ((size_t)(b*I_+j)*H_ + h)*56;
  kb[53] = m;
  kb[54] = 1.0f / S;
}

// Pass 2 (partial): block owns 16 i (it) and a j-chunk (jc of jch). thr=(h,il).
// z staged per 16-j tile in LDS (coalesced); k-side direct (L1 broadcast).
__global__ __launch_bounds__(192,3) void kC(const float* __restrict__ z,
                 const float* __restrict__ Wb, float* __restrict__ ws, int jsh) {
  int blk = blockIdx.x;
  int jch = 1 << jsh;
  int jc = blk & (jch-1); int it = (blk >> jsh) & 63; int b = blk >> (jsh+6);
  int tid = threadIdx.x; int h = tid >> 4, il = tid & 15;
  int i0 = it*16;
  int i = i0 + il;
  const float* qpQ = ws + QPQ_OFF;
  const float* kpK = ws + KPK_OFF;
  __shared__ float4 zt4[16*81];   // [i 16 stride 81][j 16 stride 5][c4]
  const float4* q4 = (const float4*)(qpQ + ((size_t)(b*I_+i)*H_ + h)*32);
  float4 qa = q4[0], qb = q4[1], qc = q4[2], qd = q4[3];
  float4 qpa = q4[4], qpb = q4[5], qpc = q4[6];
  float q2 = q4[7].x;
  float wb[16];
  #pragma unroll
  for (int c = 0; c < 16; c++) wb[c] = Wb[c*12 + h] * (W_Lc * LOG2E);
  float opts[24], opair[16], rsum = 0.f;
  #pragma unroll
  for (int n = 0; n < 24; n++) opts[n] = 0.f;
  #pragma unroll
  for (int c = 0; c < 16; c++) opair[c] = 0.f;
  int chunk = I_ >> jsh;
  int j0c = jc * chunk;
  for (int t = 0; t < (chunk >> 4); ++t) {
    int j0 = j0c + t*16;
    __syncthreads();
    for (int idx = tid; idx < 1024; idx += 192) {
      int r = idx >> 6, rem = idx & 63, jj = rem >> 2, c4 = rem & 3;
      const float4* src = (const float4*)(z + ((size_t)(b*I_ + i0 + r)*I_ + j0 + jj)*16);
      zt4[r*81 + jj*5 + c4] = src[c4];
    }
    __syncthreads();
    #pragma unroll 2
    for (int jj = 0; jj < 16; ++jj) {
      int j = j0 + jj;
      const float4* krow = (const float4*)(kpK + ((size_t)(b*I_+j)*H_ + h)*56);
      float4 k0 = krow[0], k1 = krow[1], k2v = krow[2], k3 = krow[3];
      float4 kp0 = krow[4], kp1 = krow[5], kp2 = krow[6];
      float4 tl = krow[13];
      const float4* zr = zt4 + il*81 + jj*5;
      float4 z0 = zr[0], z1 = zr[1], z2 = zr[2], z3 = zr[3];
      float s0 = qa.x*k0.x + qa.y*k0.y + qa.z*k0.z + qa.w*k0.w
               + qpa.x*kp0.x + qpa.y*kp0.y + qpa.z*kp0.z + qpa.w*kp0.w
               + z0.x*wb[0] + z0.y*wb[1] + z0.z*wb[2] + z0.w*wb[3];
      float s1 = qb.x*k1.x + qb.y*k1.y + qb.z*k1.z + qb.w*k1.w
               + qpb.x*kp1.x + qpb.y*kp1.y + qpb.z*kp1.z + qpb.w*kp1.w
               + z1.x*wb[4] + z1.y*wb[5] + z1.z*wb[6] + z1.w*wb[7];
      float s2 = qc.x*k2v.x + qc.y*k2v.y + qc.z*k2v.z + qc.w*k2v.w
               + qpc.x*kp2.x + qpc.y*kp2.y + qpc.z*kp2.z + qpc.w*kp2.w
               + z2.x*wb[8] + z2.y*wb[9] + z2.z*wb[10] + z2.w*wb[11];
      float s3 = qd.x*k3.x + qd.y*k3.y + qd.z*k3.z + qd.w*k3.w
               + z3.x*wb[12] + z3.y*wb[13] + z3.z*wb[14] + z3.w*wb[15]
               + q2 + tl.x;
      float l2 = (s0 + s1) + (s2 + s3);
      float w = __builtin_amdgcn_exp2f(l2 - tl.y) * tl.z;
      rsum += w;
      opair[0] += w*z0.x; opair[1] += w*z0.y; opair[2] += w*z0.z; opair[3] += w*z0.w;
      opair[4] += w*z1.x; opair[5] += w*z1.y; opair[6] += w*z1.z; opair[7] += w*z1.w;
      opair[8] += w*z2.x; opair[9] += w*z2.y; opair[10] += w*z2.z; opair[11] += w*z2.w;
      opair[12] += w*z3.x; opair[13] += w*z3.y; opair[14] += w*z3.z; opair[15] += w*z3.w;
      float4 v0 = krow[7], v1 = krow[8];
      opts[0] += w*v0.x; opts[1] += w*v0.y; opts[2] += w*v0.z; opts[3] += w*v0.w;
      opts[4] += w*v1.x; opts[5] += w*v1.y; opts[6] += w*v1.z; opts[7] += w*v1.w;
      float4 v2 = krow[9], v3 = krow[10];
      opts[8] += w*v2.x; opts[9] += w*v2.y; opts[10] += w*v2.z; opts[11] += w*v2.w;
      opts[12] += w*v3.x; opts[13] += w*v3.y; opts[14] += w*v3.z; opts[15] += w*v3.w;
      float4 v4 = krow[11], v5 = krow[12];
      opts[16] += w*v4.x; opts[17] += w*v4.y; opts[18] += w*v4.z; opts[19] += w*v4.w;
      opts[20] += w*v5.x; opts[21] += w*v5.y; opts[22] += w*v5.z; opts[23] += w*v5.w;
    }
  }
  float* ab = ws + ACC2_OFF + ((size_t)(b*I_+i)*jch + jc)*512;
  #pragma unroll
  for (int n = 0; n < 24; n++) ab[h*24 + n] = opts[n];
  #pragma unroll
  for (int c = 0; c < 16; c++) ab[288 + h*16 + c] = opair[c];
  ab[480 + h] = rsum;
}

// Epilogue: reduce jch partials, build cat[8][768], out = cat @ Wout + bout.
__global__ __launch_bounds__(256) void kD(const float* __restrict__ Wout, const float* __restrict__ bout,
                 const float* __restrict__ ws, float* __restrict__ out, int jsh) {
  int jch = 1 << jsh;
  int blk = blockIdx.x;
  int b = blk >> 7; int i0 = (blk & 127) << 3;
  int tid = threadIdx.x;
  __shared__ float accs[8*512];
  __shared__ float cat[8*776];
  const float* acc2 = ws + ACC2_OFF;
  for (int idx = tid; idx < 8*512; idx += 256) {
    int r = idx >> 9, f = idx & 511;
    const float* src = acc2 + (size_t)(b*I_+i0+r)*jch*512 + f;
    float ssum = 0.f;
    for (int jc = 0; jc < jch; jc++) ssum += src[jc*512];
    accs[idx] = ssum;
  }
  __syncthreads();
  const float* vv = ws + V_OFF;
  for (int idx = tid; idx < 8*768; idx += 256) {
    int r = idx / 768, f = idx - r*768;
    int i = i0 + r;
    const float* ab = accs + r*512;
    float val;
    if (f < 192) {
      int h = f >> 4, c = f & 15;
      val = vv[((size_t)(b*I_+i)*H_ + h)*16 + c] * ab[480 + h];
    } else if (f < 384) {
      val = ab[288 + (f - 192)];
    } else if (f < 672) {
      val = ab[f - 384];
    } else {
      int g = f - 672; int base = (g >> 3)*24 + (g & 7)*3;
      float x0 = ab[base], x1 = ab[base+1], x2 = ab[base+2];
      val = sqrtf(fmaxf(x0*x0 + x1*x1 + x2*x2, 1e-12f));
    }
    cat[r*776 + f] = val;
  }
  __syncthreads();
  if (tid < 128) {
    int r = tid >> 4, c = tid & 15;
    float sum = bout[c];
    const float* cr = cat + r*776;
    float a0 = 0.f, a1 = 0.f, a2 = 0.f, a3 = 0.f;
    for (int f = 0; f < 768; f += 4) {
      a0 += cr[f]   * Wout[f*16 + c];
      a1 += cr[f+1] * Wout[(f+1)*16 + c];
      a2 += cr[f+2] * Wout[(f+2)*16 + c];
      a3 += cr[f+3] * Wout[(f+3)*16 + c];
    }
    out[((size_t)(b*I_) + i0 + r)*16 + c] = sum + (a0+a1) + (a2+a3);
  }
}

extern "C" void kernel_launch(void* const* d_in, const int* in_sizes, int n_in,
                              void* d_out, int out_size, void* d_ws, size_t ws_size,
                              hipStream_t stream) {
  const float* s    = (const float*)d_in[0];
  const float* z    = (const float*)d_in[1];
  const float* R    = (const float*)d_in[2];
  const float* t    = (const float*)d_in[3];
  const float* Wq   = (const float*)d_in[4];
  const float* Wk   = (const float*)d_in[5];
  const float* Wv   = (const float*)d_in[6];
  const float* Wb   = (const float*)d_in[7];
  const float* Wqp  = (const float*)d_in[8];
  const float* Wkp  = (const float*)d_in[9];
  const float* Wvp  = (const float*)d_in[10];
  const float* gam  = (const float*)d_in[11];
  const float* Wout = (const float*)d_in[12];
  const float* bout = (const float*)d_in[13];
  float* out = (float*)d_out;
  float* ws = (float*)d_ws;

  // pick largest jch (power of 2, <=16) whose partial buffer fits ws
  int jsh = 4;
  while (jsh > 0) {
    size_t need = ((size_t)ACC2_OFF + (size_t)B_*I_*(1u<<jsh)*512) * 4u;
    if (need <= ws_size) break;
    jsh--;
  }

  hipLaunchKernelGGL(kA, dim3(B_*I_), dim3(192), 0, stream,
                     s, R, t, Wq, Wk, Wv, Wqp, Wkp, Wvp, gam, ws);
  hipLaunchKernelGGL(kB, dim3(B_*64*ICH), dim3(192), 0, stream, z, Wb, ws);
  hipLaunchKernelGGL(kB2, dim3(B_*64), dim3(192), 0, stream, ws);
  hipLaunchKernelGGL(kC, dim3(B_*64*(1<<jsh)), dim3(192), 0, stream, z, Wb, ws, jsh);
  hipLaunchKernelGGL(kD, dim3(B_*(I_/8)), dim3(256), 0, stream, Wout, bout, ws, out, jsh);
}

// Round 4
// 216.567 us; speedup vs baseline: 5.9430x; 1.9900x over previous
//
#include <hip/hip_runtime.h>
#include <hip/hip_bf16.h>
#include <math.h>

#define B_ 2
#define I_ 1024
#define C_ 16
#define H_ 12
#define ICH 16

__device__ __constant__ float kW_C = 0.23570226039551584f; // sqrt(2/(9*4))
#define W_Lc 0.5773502691896258f
#define LOG2E 1.4426950408889634f

typedef _Float16 hf;
typedef hf hf2 __attribute__((ext_vector_type(2)));
typedef unsigned int u32;

template <typename T, typename F>
__device__ inline T bc(F f) { return __builtin_bit_cast(T, f); }

__device__ inline float fdot2f(u32 a, u32 b, float c) {
#if __has_builtin(__builtin_amdgcn_fdot2)
  return __builtin_amdgcn_fdot2(bc<hf2>(a), bc<hf2>(b), c, false);
#else
  hf2 x = bc<hf2>(a), y = bc<hf2>(b);
  return c + (float)x[0] * (float)y[0] + (float)x[1] * (float)y[1];
#endif
}

__device__ inline u32 pkrtz(float lo, float hi) {
#if __has_builtin(__builtin_amdgcn_cvt_pkrtz)
  return bc<u32>(__builtin_amdgcn_cvt_pkrtz(lo, hi));
#else
  hf2 t; t[0] = (hf)lo; t[1] = (hf)hi; return bc<u32>(t);
#endif
}

__device__ inline u32 permlo(u32 hiw, u32 low) { // (low16 of low, low16 of hiw)
#if __has_builtin(__builtin_amdgcn_perm)
  return __builtin_amdgcn_perm(hiw, low, 0x05040100u);
#else
  return (low & 0xffffu) | (hiw << 16);
#endif
}
__device__ inline u32 permhi(u32 hiw, u32 low) { // (hi16 of low, hi16 of hiw)
#if __has_builtin(__builtin_amdgcn_perm)
  return __builtin_amdgcn_perm(hiw, low, 0x07060302u);
#else
  return (low >> 16) | (hiw & 0xffff0000u);
#endif
}

__device__ inline void ld16lds(const ushort* p, u32* d) {
  const uint4* q = (const uint4*)p;
  uint4 a = q[0], b = q[1], c = q[2], e = q[3];
  d[0]=a.x; d[1]=a.y; d[2]=a.z; d[3]=a.w;
  d[4]=b.x; d[5]=b.y; d[6]=b.z; d[7]=b.w;
  d[8]=c.x; d[9]=c.y; d[10]=c.z; d[11]=c.w;
  d[12]=e.x; d[13]=e.y; d[14]=e.z; d[15]=e.w;
}
__device__ inline void ld8lds(const ushort* p, u32* d) {
  const uint4* q = (const uint4*)p;
  uint4 a = q[0], b = q[1];
  d[0]=a.x; d[1]=a.y; d[2]=a.z; d[3]=a.w;
  d[4]=b.x; d[5]=b.y; d[6]=b.z; d[7]=b.w;
}

// ws layout (float units):
// QF16 [B][I][392] hf  (per h: 32 feats: 0:16 q', 16:28 qp'', 28 cw*q2, 29 =1, 30,31 =0)
// KF16 [B][I][392] hf  (per h: 0:16 k, 16:28 kp, 28 =1, 29 cw*k2, 30,31 =0)
// VPF  [B][I][288] hf  (per h: 24 = vpts p*3+x)
// VV   [B][I][192] f32
// SM   [B][12][1024][2] f32 (m, 1/S)
// pm   [B][64][ICH][192] float2
// acc2 [B][I][jch][512] f32
#define QF16_OFF 0
#define QF16_SZ (B_*I_*196)
#define KF16_OFF (QF16_OFF + QF16_SZ)
#define KF16_SZ QF16_SZ
#define VPF_OFF (KF16_OFF + KF16_SZ)
#define VPF_SZ (B_*I_*144)
#define VV_OFF (VPF_OFF + VPF_SZ)
#define VV_SZ (B_*I_*192)
#define SM_OFF (VV_OFF + VV_SZ)
#define SM_SZ (B_*12*1024*2)
#define PM_OFF (SM_OFF + SM_SZ)
#define PM_SZ (B_*64*ICH*192*2)
#define ACC2_OFF (PM_OFF + PM_SZ)

__global__ __launch_bounds__(192) void kA(const float* __restrict__ s, const float* __restrict__ R,
                 const float* __restrict__ t, const float* __restrict__ Wq,
                 const float* __restrict__ Wk, const float* __restrict__ Wv,
                 const float* __restrict__ Wqp, const float* __restrict__ Wkp,
                 const float* __restrict__ Wvp, const float* __restrict__ gam,
                 float* __restrict__ ws) {
  int blk = blockIdx.x;
  int b = blk >> 10, i = blk & 1023;
  int tid = threadIdx.x;
  __shared__ float sl[16], rl[9], tl[3], part[96];
  if (tid < 16) sl[tid] = s[(b*I_ + i)*C_ + tid];
  else if (tid < 25) rl[tid-16] = R[(size_t)(b*I_+i)*9 + (tid-16)];
  else if (tid < 28) tl[tid-25] = t[(size_t)(b*I_+i)*3 + (tid-25)];
  __syncthreads();
  hf* QF  = (hf*)(ws + QF16_OFF) + (size_t)(b*I_+i)*392;
  hf* KF  = (hf*)(ws + KF16_OFF) + (size_t)(b*I_+i)*392;
  hf* VPF = (hf*)(ws + VPF_OFF) + (size_t)(b*I_+i)*288;
  float* vv = ws + VV_OFF + (size_t)(b*I_+i)*192;
  // phase 1: q/k/v projections; tid == h*16+c
  {
    int hc = tid; int h = hc >> 4, c = hc & 15;
    float aq = 0.f, ak = 0.f, av = 0.f;
    #pragma unroll
    for (int ci = 0; ci < 16; ci++) {
      float sv = sl[ci];
      aq += sv * Wq[ci*192 + hc];
      ak += sv * Wk[ci*192 + hc];
      av += sv * Wv[ci*192 + hc];
    }
    const float s_qk = 0.25f * W_Lc * LOG2E;
    QF[h*32 + c] = (hf)(aq * s_qk);
    KF[h*32 + c] = (hf)ak;
    vv[hc] = av;
  }
  // phase 2: points (48 qp, 48 kp, 96 vp tasks)
  {
    float raw[3], px[3];
    if (tid < 96) {
      bool isq = tid < 48;
      int n = isq ? tid : tid - 48;
      const float* W = isq ? Wqp : Wkp;
      #pragma unroll
      for (int x = 0; x < 3; x++) {
        float a2 = 0.f;
        #pragma unroll
        for (int ci = 0; ci < 16; ci++) a2 += sl[ci] * W[ci*144 + n*3 + x];
        raw[x] = a2;
      }
      #pragma unroll
      for (int x = 0; x < 3; x++)
        px[x] = rl[x*3]*raw[0] + rl[x*3+1]*raw[1] + rl[x*3+2]*raw[2] + tl[x];
      int h = n >> 2, p = n & 3;
      part[tid] = px[0]*px[0] + px[1]*px[1] + px[2]*px[2];
      if (isq) {
        float g = gam[h];
        float sp = log1pf(expf(g));
        float coef2 = -0.5f * kW_C * sp * W_Lc * LOG2E;
        #pragma unroll
        for (int x = 0; x < 3; x++) QF[h*32 + 16 + p*3 + x] = (hf)(px[x] * (-2.0f * coef2));
      } else {
        #pragma unroll
        for (int x = 0; x < 3; x++) KF[h*32 + 16 + p*3 + x] = (hf)px[x];
      }
    } else {
      int n = tid - 96;
      #pragma unroll
      for (int x = 0; x < 3; x++) {
        float a2 = 0.f;
        #pragma unroll
        for (int ci = 0; ci < 16; ci++) a2 += sl[ci] * Wvp[ci*288 + n*3 + x];
        raw[x] = a2;
      }
      #pragma unroll
      for (int x = 0; x < 3; x++)
        px[x] = rl[x*3]*raw[0] + rl[x*3+1]*raw[1] + rl[x*3+2]*raw[2] + tl[x];
      int h = n >> 3, p = n & 7;
      #pragma unroll
      for (int x = 0; x < 3; x++) VPF[h*24 + p*3 + x] = (hf)px[x];
    }
  }
  __syncthreads();
  if (tid < 24) {
    int h = tid % 12; bool isq = tid < 12;
    float g = gam[h];
    float sp = log1pf(expf(g));
    float coef2 = -0.5f * kW_C * sp * W_Lc * LOG2E;
    float s2 = 0.f;
    int base = isq ? h*4 : 48 + h*4;
    #pragma unroll
    for (int p = 0; p < 4; p++) s2 += part[base + p];
    if (isq) {
      QF[h*32 + 28] = (hf)(coef2 * s2);
      QF[h*32 + 29] = (hf)1.0f;
      QF[h*32 + 30] = (hf)0.0f;
      QF[h*32 + 31] = (hf)0.0f;
    } else {
      KF[h*32 + 28] = (hf)1.0f;
      KF[h*32 + 29] = (hf)(coef2 * s2);
      KF[h*32 + 30] = (hf)0.0f;
      KF[h*32 + 31] = (hf)0.0f;
    }
  }
}

// Pass 1 (stats): block = (b, jt of 64, ic of ICH). 16 j, 64 i. thr=(h,jl).
__global__ __launch_bounds__(192,4) void kB(const float* __restrict__ z,
                 const float* __restrict__ Wb, float* __restrict__ ws) {
  int blk = blockIdx.x;
  int ic = blk & (ICH-1); int jt = (blk >> 4) & 63; int b = blk >> 10;
  int tid = threadIdx.x; int h = tid >> 4, jl = tid & 15;
  int j = jt*16 + jl;
  __shared__ ushort qlds[16*392];   // [i][h*32+f] hf
  __shared__ ushort zlds[16*544];   // [i][jj*32 + c] hf (i-stride 544)
  u32 kf[16];
  {
    const ushort* KF = (const ushort*)((const hf*)(ws + KF16_OFF)) + (size_t)(b*I_+j)*392 + h*32;
    ld16lds(KF, kf);   // global, aligned, same pattern works
  }
  u32 wb2[8];
  #pragma unroll
  for (int p = 0; p < 8; p++)
    wb2[p] = pkrtz(Wb[(2*p)*12 + h] * (W_Lc*LOG2E), Wb[(2*p+1)*12 + h] * (W_Lc*LOG2E));
  float m = -1e30f, S = 0.f;
  int ibase = ic*64;
  for (int t = 0; t < 4; ++t) {
    int i0 = ibase + t*16;
    __syncthreads();
    {
      const uint4* qsrc = (const uint4*)((const hf*)(ws + QF16_OFF) + (size_t)(b*I_+i0)*392);
      uint4* qdst = (uint4*)qlds;
      for (int idx = tid; idx < 784; idx += 192) qdst[idx] = qsrc[idx];
    }
    for (int idx = tid; idx < 1024; idx += 192) {
      int r = idx >> 6, jj = (idx >> 2) & 15, c4 = idx & 3;
      float4 v = *(const float4*)(z + ((size_t)(b*I_ + i0 + r)*I_ + jt*16 + jj)*16 + c4*4);
      uint2 pk = make_uint2(pkrtz(v.x, v.y), pkrtz(v.z, v.w));
      *(uint2*)&zlds[r*544 + jj*32 + c4*4] = pk;
    }
    __syncthreads();
    #pragma unroll 1
    for (int ip = 0; ip < 8; ++ip) {
      u32 q0[16], q1[16], z0[8], z1[8];
      ld16lds(&qlds[(2*ip)*392 + h*32], q0);
      ld16lds(&qlds[(2*ip+1)*392 + h*32], q1);
      ld8lds(&zlds[(2*ip)*544 + jl*32], z0);
      ld8lds(&zlds[(2*ip+1)*544 + jl*32], z1);
      float a0 = 0.f, a1 = 0.f, b0 = 0.f, b1 = 0.f;
      #pragma unroll
      for (int p = 0; p < 16; p += 2) {
        a0 = fdot2f(q0[p], kf[p], a0);
        b0 = fdot2f(q0[p+1], kf[p+1], b0);
        a1 = fdot2f(q1[p], kf[p], a1);
        b1 = fdot2f(q1[p+1], kf[p+1], b1);
      }
      #pragma unroll
      for (int p = 0; p < 8; p += 2) {
        a0 = fdot2f(z0[p], wb2[p], a0);
        b0 = fdot2f(z0[p+1], wb2[p+1], b0);
        a1 = fdot2f(z1[p], wb2[p], a1);
        b1 = fdot2f(z1[p+1], wb2[p+1], b1);
      }
      float l0 = a0 + b0, l1 = a1 + b1;
      float mn = fmaxf(m, fmaxf(l0, l1));
      S = S * __builtin_amdgcn_exp2f(m - mn)
        + __builtin_amdgcn_exp2f(l0 - mn) + __builtin_amdgcn_exp2f(l1 - mn);
      m = mn;
    }
  }
  float2* pm = (float2*)(ws + PM_OFF);
  pm[((size_t)(b*64+jt)*ICH + ic)*192 + tid] = make_float2(m, S);
}

// merge ICH partial (m,S) -> SM[b][h][j] = (m, 1/S)
__global__ __launch_bounds__(192) void kB2(float* __restrict__ ws) {
  int blk = blockIdx.x; int jt = blk & 63, b = blk >> 6;
  int tid = threadIdx.x; int h = tid >> 4, jl = tid & 15;
  const float2* pm = (const float2*)(ws + PM_OFF) + (size_t)(b*64+jt)*ICH*192 + tid;
  float m = -1e30f, S = 0.f;
  #pragma unroll
  for (int ic = 0; ic < ICH; ic++) {
    float2 p = pm[ic*192];
    float mn = fmaxf(m, p.x);
    S = S * __builtin_amdgcn_exp2f(m - mn) + p.y * __builtin_amdgcn_exp2f(p.x - mn);
    m = mn;
  }
  int j = jt*16 + jl;
  float* sm = ws + SM_OFF + ((size_t)((b*12+h)*1024) + j)*2;
  sm[0] = m;
  sm[1] = 1.0f / S;
}

// Pass 2: block = (b, it of 64, jc of jch). 16 i, stream I_/jch j. thr=(h,il).
__global__ __launch_bounds__(192,3) void kC(const float* __restrict__ z,
                 const float* __restrict__ Wb, float* __restrict__ ws, int jsh) {
  int blk = blockIdx.x;
  int jch = 1 << jsh;
  int jc = blk & (jch-1); int it = (blk >> jsh) & 63; int b = blk >> (jsh+6);
  int tid = threadIdx.x; int h = tid >> 4, il = tid & 15;
  int i = it*16 + il;
  __shared__ ushort klds[16*392];     // [jj][h*32+f]
  __shared__ ushort zlds[16*544];     // [r(i)][jj*32+c]
  __shared__ ushort vplds[8*12*48];   // [jp][h][24 pairs]
  __shared__ float4 slds[12*8];       // [h][jp] = (m0, is0, m1, is1)
  u32 qr[16];
  {
    const ushort* QF = (const ushort*)((const hf*)(ws + QF16_OFF)) + (size_t)(b*I_+i)*392 + h*32;
    ld16lds(QF, qr);
  }
  u32 wb2[8];
  #pragma unroll
  for (int p = 0; p < 8; p++)
    wb2[p] = pkrtz(Wb[(2*p)*12 + h] * (W_Lc*LOG2E), Wb[(2*p+1)*12 + h] * (W_Lc*LOG2E));
  float opts[24], opair[16], rsum = 0.f;
  #pragma unroll
  for (int n = 0; n < 24; n++) opts[n] = 0.f;
  #pragma unroll
  for (int c = 0; c < 16; c++) opair[c] = 0.f;
  int chunk = I_ >> jsh;
  int nt = chunk >> 4;
  for (int t = 0; t < nt; ++t) {
    int j0 = jc*chunk + t*16;
    __syncthreads();
    {
      const uint4* ksrc = (const uint4*)((const hf*)(ws + KF16_OFF) + (size_t)(b*I_+j0)*392);
      uint4* kdst = (uint4*)klds;
      for (int idx = tid; idx < 784; idx += 192) kdst[idx] = ksrc[idx];
    }
    for (int idx = tid; idx < 1024; idx += 192) {
      int r = idx >> 6, jj = (idx >> 2) & 15, c4 = idx & 3;
      float4 v = *(const float4*)(z + ((size_t)(b*I_ + it*16 + r)*I_ + j0 + jj)*16 + c4*4);
      uint2 pk = make_uint2(pkrtz(v.x, v.y), pkrtz(v.z, v.w));
      *(uint2*)&zlds[r*544 + jj*32 + c4*4] = pk;
    }
    for (int idx = tid; idx < 576; idx += 192) {
      int jp = idx / 72, rem = idx - jp*72;
      int hh = rem / 6, n4 = rem - hh*6;
      const ushort* vsrc = (const ushort*)((const hf*)(ws + VPF_OFF)) + (size_t)(b*I_ + j0 + 2*jp)*288 + hh*24 + n4*4;
      uint2 a = *(const uint2*)vsrc;
      uint2 c = *(const uint2*)(vsrc + 288);
      uint4 o = make_uint4(permlo(c.x, a.x), permhi(c.x, a.x),
                           permlo(c.y, a.y), permhi(c.y, a.y));
      *(uint4*)&vplds[(jp*12 + hh)*48 + n4*8] = o;
    }
    if (tid < 192) {
      int hh = tid >> 4, jj = tid & 15;
      float2 v = *(const float2*)(ws + SM_OFF + ((size_t)((b*12+hh)*1024) + j0 + jj)*2);
      ((float2*)slds)[hh*16 + jj] = v;
    }
    __syncthreads();
    #pragma unroll 1
    for (int jp = 0; jp < 8; ++jp) {
      u32 k0[16], k1[16], z0[8], z1[8];
      ld16lds(&klds[(2*jp)*392 + h*32], k0);
      ld16lds(&klds[(2*jp+1)*392 + h*32], k1);
      ld8lds(&zlds[il*544 + (2*jp)*32], z0);
      ld8lds(&zlds[il*544 + (2*jp+1)*32], z1);
      float a0 = 0.f, a1 = 0.f, b0 = 0.f, b1 = 0.f;
      #pragma unroll
      for (int p = 0; p < 16; p += 2) {
        a0 = fdot2f(qr[p], k0[p], a0);
        b0 = fdot2f(qr[p+1], k0[p+1], b0);
        a1 = fdot2f(qr[p], k1[p], a1);
        b1 = fdot2f(qr[p+1], k1[p+1], b1);
      }
      #pragma unroll
      for (int p = 0; p < 8; p += 2) {
        a0 = fdot2f(z0[p], wb2[p], a0);
        b0 = fdot2f(z0[p+1], wb2[p+1], b0);
        a1 = fdot2f(z1[p], wb2[p], a1);
        b1 = fdot2f(z1[p+1], wb2[p+1], b1);
      }
      float l0 = a0 + b0, l1 = a1 + b1;
      float4 st = slds[h*8 + jp];
      float w0 = __builtin_amdgcn_exp2f(l0 - st.x) * st.y;
      float w1 = __builtin_amdgcn_exp2f(l1 - st.z) * st.w;
      rsum += w0 + w1;
      u32 w2 = pkrtz(w0, w1);
      #pragma unroll
      for (int p = 0; p < 8; p++) {
        u32 lo = permlo(z1[p], z0[p]);
        u32 hi = permhi(z1[p], z0[p]);
        opair[2*p]   = fdot2f(w2, lo, opair[2*p]);
        opair[2*p+1] = fdot2f(w2, hi, opair[2*p+1]);
      }
      const ushort* vp = &vplds[(jp*12 + h)*48];
      #pragma unroll
      for (int n4 = 0; n4 < 6; n4++) {
        uint4 v4 = *(const uint4*)(vp + n4*8);
        opts[n4*4+0] = fdot2f(w2, v4.x, opts[n4*4+0]);
        opts[n4*4+1] = fdot2f(w2, v4.y, opts[n4*4+1]);
        opts[n4*4+2] = fdot2f(w2, v4.z, opts[n4*4+2]);
        opts[n4*4+3] = fdot2f(w2, v4.w, opts[n4*4+3]);
      }
    }
  }
  float* ab = ws + ACC2_OFF + ((size_t)(b*I_+i)*jch + jc)*512;
  #pragma unroll
  for (int n = 0; n < 24; n++) ab[h*24 + n] = opts[n];
  #pragma unroll
  for (int c = 0; c < 16; c++) ab[288 + h*16 + c] = opair[c];
  ab[480 + h] = rsum;
}

// Epilogue: reduce jch partials, build cat[8][768], out = cat @ Wout + bout.
__global__ __launch_bounds__(256) void kD(const float* __restrict__ Wout, const float* __restrict__ bout,
                 const float* __restrict__ ws, float* __restrict__ out, int jsh) {
  int jch = 1 << jsh;
  int blk = blockIdx.x;
  int b = blk >> 7; int i0 = (blk & 127) << 3;
  int tid = threadIdx.x;
  __shared__ float accs[8*512];
  __shared__ float cat[8*776];
  const float* acc2 = ws + ACC2_OFF;
  for (int idx = tid; idx < 8*512; idx += 256) {
    int r = idx >> 9, f = idx & 511;
    const float* src = acc2 + (size_t)(b*I_+i0+r)*jch*512 + f;
    float ssum = 0.f;
    for (int jc = 0; jc < jch; jc++) ssum += src[jc*512];
    accs[idx] = ssum;
  }
  __syncthreads();
  const float* vv = ws + VV_OFF;
  for (int idx = tid; idx < 8*768; idx += 256) {
    int r = idx / 768, f = idx - r*768;
    int i = i0 + r;
    const float* ab = accs + r*512;
    float val;
    if (f < 192) {
      int h = f >> 4, c = f & 15;
      val = vv[(size_t)(b*I_+i)*192 + h*16 + c] * ab[480 + h];
    } else if (f < 384) {
      val = ab[288 + (f - 192)];
    } else if (f < 672) {
      val = ab[f - 384];
    } else {
      int g = f - 672; int base = (g >> 3)*24 + (g & 7)*3;
      float x0 = ab[base], x1 = ab[base+1], x2 = ab[base+2];
      val = sqrtf(fmaxf(x0*x0 + x1*x1 + x2*x2, 1e-12f));
    }
    cat[r*776 + f] = val;
  }
  __syncthreads();
  if (tid < 128) {
    int r = tid >> 4, c = tid & 15;
    float sum = bout[c];
    const float* cr = cat + r*776;
    float a0 = 0.f, a1 = 0.f, a2 = 0.f, a3 = 0.f;
    for (int f = 0; f < 768; f += 4) {
      a0 += cr[f]   * Wout[f*16 + c];
      a1 += cr[f+1] * Wout[(f+1)*16 + c];
      a2 += cr[f+2] * Wout[(f+2)*16 + c];
      a3 += cr[f+3] * Wout[(f+3)*16 + c];
    }
    out[((size_t)(b*I_) + i0 + r)*16 + c] = sum + (a0+a1) + (a2+a3);
  }
}

extern "C" void kernel_launch(void* const* d_in, const int* in_sizes, int n_in,
                              void* d_out, int out_size, void* d_ws, size_t ws_size,
                              hipStream_t stream) {
  const float* s    = (const float*)d_in[0];
  const float* z    = (const float*)d_in[1];
  const float* R    = (const float*)d_in[2];
  const float* t    = (const float*)d_in[3];
  const float* Wq   = (const float*)d_in[4];
  const float* Wk   = (const float*)d_in[5];
  const float* Wv   = (const float*)d_in[6];
  const float* Wb   = (const float*)d_in[7];
  const float* Wqp  = (const float*)d_in[8];
  const float* Wkp  = (const float*)d_in[9];
  const float* Wvp  = (const float*)d_in[10];
  const float* gam  = (const float*)d_in[11];
  const float* Wout = (const float*)d_in[12];
  const float* bout = (const float*)d_in[13];
  float* out = (float*)d_out;
  float* ws = (float*)d_ws;

  // pick largest jch (power of 2, <=8) whose partial buffer fits ws
  int jsh = 3;
  while (jsh > 0) {
    size_t need = ((size_t)ACC2_OFF + (size_t)B_*I_*(1u<<jsh)*512) * 4u;
    if (need <= ws_size) break;
    jsh--;
  }

  hipLaunchKernelGGL(kA, dim3(B_*I_), dim3(192), 0, stream,
                     s, R, t, Wq, Wk, Wv, Wqp, Wkp, Wvp, gam, ws);
  hipLaunchKernelGGL(kB, dim3(B_*64*ICH), dim3(192), 0, stream, z, Wb, ws);
  hipLaunchKernelGGL(kB2, dim3(B_*64), dim3(192), 0, stream, ws);
  hipLaunchKernelGGL(kC, dim3(B_*64*(1<<jsh)), dim3(192), 0, stream, z, Wb, ws, jsh);
  hipLaunchKernelGGL(kD, dim3(B_*(I_/8)), dim3(256), 0, stream, Wout, bout, ws, out, jsh);
}

// Round 5
// 210.827 us; speedup vs baseline: 6.1048x; 1.0272x over previous
//
#include <hip/hip_runtime.h>
#include <hip/hip_bf16.h>
#include <math.h>

#define B_ 2
#define I_ 1024
#define C_ 16
#define H_ 12
#define ICH 8

__device__ __constant__ float kW_C = 0.23570226039551584f; // sqrt(2/(9*4))
#define W_Lc 0.5773502691896258f
#define LOG2E 1.4426950408889634f

typedef _Float16 hf;
typedef hf hf2 __attribute__((ext_vector_type(2)));
typedef unsigned int u32;

template <typename T, typename F>
__device__ inline T bc(F f) { return __builtin_bit_cast(T, f); }

__device__ inline float fdot2f(u32 a, u32 b, float c) {
#if __has_builtin(__builtin_amdgcn_fdot2)
  return __builtin_amdgcn_fdot2(bc<hf2>(a), bc<hf2>(b), c, false);
#else
  hf2 x = bc<hf2>(a), y = bc<hf2>(b);
  return c + (float)x[0] * (float)y[0] + (float)x[1] * (float)y[1];
#endif
}

__device__ inline u32 pkrtz(float lo, float hi) {
#if __has_builtin(__builtin_amdgcn_cvt_pkrtz)
  return bc<u32>(__builtin_amdgcn_cvt_pkrtz(lo, hi));
#else
  hf2 t; t[0] = (hf)lo; t[1] = (hf)hi; return bc<u32>(t);
#endif
}

__device__ inline u32 permlo(u32 hiw, u32 low) { // (low16 of low, low16 of hiw)
#if __has_builtin(__builtin_amdgcn_perm)
  return __builtin_amdgcn_perm(hiw, low, 0x05040100u);
#else
  return (low & 0xffffu) | (hiw << 16);
#endif
}
__device__ inline u32 permhi(u32 hiw, u32 low) { // (hi16 of low, hi16 of hiw)
#if __has_builtin(__builtin_amdgcn_perm)
  return __builtin_amdgcn_perm(hiw, low, 0x07060302u);
#else
  return (low >> 16) | (hiw & 0xffff0000u);
#endif
}

__device__ inline void ld16lds(const ushort* p, u32* d) {
  const uint4* q = (const uint4*)p;
  uint4 a = q[0], b = q[1], c = q[2], e = q[3];
  d[0]=a.x; d[1]=a.y; d[2]=a.z; d[3]=a.w;
  d[4]=b.x; d[5]=b.y; d[6]=b.z; d[7]=b.w;
  d[8]=c.x; d[9]=c.y; d[10]=c.z; d[11]=c.w;
  d[12]=e.x; d[13]=e.y; d[14]=e.z; d[15]=e.w;
}
__device__ inline void ld8lds(const ushort* p, u32* d) {
  const uint4* q = (const uint4*)p;
  uint4 a = q[0], b = q[1];
  d[0]=a.x; d[1]=a.y; d[2]=a.z; d[3]=a.w;
  d[4]=b.x; d[5]=b.y; d[6]=b.z; d[7]=b.w;
}

// ws layout (float units):
// QF16 [B][I][392] hf  (per h: 32 feats: 0:16 q', 16:28 qp'', 28 cw*q2, 29 =1, 30,31 =0)
// KF16 [B][I][392] hf  (per h: 0:16 k, 16:28 kp, 28 =1, 29 cw*k2, 30,31 =0)
// VPF  [B][I][288] hf  (per h: 24 = vpts p*3+x)
// VV   [B][I][192] f32
// SM   [B][12][1024][2] f32 (m, 1/S)
// pm   [B][64][ICH][192] float2
// acc2 [B][I][jch][512] f32
#define QF16_OFF 0
#define QF16_SZ (B_*I_*196)
#define KF16_OFF (QF16_OFF + QF16_SZ)
#define KF16_SZ QF16_SZ
#define VPF_OFF (KF16_OFF + KF16_SZ)
#define VPF_SZ (B_*I_*144)
#define VV_OFF (VPF_OFF + VPF_SZ)
#define VV_SZ (B_*I_*192)
#define SM_OFF (VV_OFF + VV_SZ)
#define SM_SZ (B_*12*1024*2)
#define PM_OFF (SM_OFF + SM_SZ)
#define PM_SZ (B_*64*ICH*192*2)
#define ACC2_OFF (PM_OFF + PM_SZ)

__global__ __launch_bounds__(192) void kA(const float* __restrict__ s, const float* __restrict__ R,
                 const float* __restrict__ t, const float* __restrict__ Wq,
                 const float* __restrict__ Wk, const float* __restrict__ Wv,
                 const float* __restrict__ Wqp, const float* __restrict__ Wkp,
                 const float* __restrict__ Wvp, const float* __restrict__ gam,
                 float* __restrict__ ws) {
  int blk = blockIdx.x;
  int b = blk >> 10, i = blk & 1023;
  int tid = threadIdx.x;
  __shared__ float sl[16], rl[9], tl[3], part[96];
  if (tid < 16) sl[tid] = s[(b*I_ + i)*C_ + tid];
  else if (tid < 25) rl[tid-16] = R[(size_t)(b*I_+i)*9 + (tid-16)];
  else if (tid < 28) tl[tid-25] = t[(size_t)(b*I_+i)*3 + (tid-25)];
  __syncthreads();
  hf* QF  = (hf*)(ws + QF16_OFF) + (size_t)(b*I_+i)*392;
  hf* KF  = (hf*)(ws + KF16_OFF) + (size_t)(b*I_+i)*392;
  hf* VPF = (hf*)(ws + VPF_OFF) + (size_t)(b*I_+i)*288;
  float* vv = ws + VV_OFF + (size_t)(b*I_+i)*192;
  // phase 1: q/k/v projections; tid == h*16+c
  {
    int hc = tid; int h = hc >> 4, c = hc & 15;
    float aq = 0.f, ak = 0.f, av = 0.f;
    #pragma unroll
    for (int ci = 0; ci < 16; ci++) {
      float sv = sl[ci];
      aq += sv * Wq[ci*192 + hc];
      ak += sv * Wk[ci*192 + hc];
      av += sv * Wv[ci*192 + hc];
    }
    const float s_qk = 0.25f * W_Lc * LOG2E;
    QF[h*32 + c] = (hf)(aq * s_qk);
    KF[h*32 + c] = (hf)ak;
    vv[hc] = av;
  }
  // phase 2: points (48 qp, 48 kp, 96 vp tasks)
  {
    float raw[3], px[3];
    if (tid < 96) {
      bool isq = tid < 48;
      int n = isq ? tid : tid - 48;
      const float* W = isq ? Wqp : Wkp;
      #pragma unroll
      for (int x = 0; x < 3; x++) {
        float a2 = 0.f;
        #pragma unroll
        for (int ci = 0; ci < 16; ci++) a2 += sl[ci] * W[ci*144 + n*3 + x];
        raw[x] = a2;
      }
      #pragma unroll
      for (int x = 0; x < 3; x++)
        px[x] = rl[x*3]*raw[0] + rl[x*3+1]*raw[1] + rl[x*3+2]*raw[2] + tl[x];
      int h = n >> 2, p = n & 3;
      part[tid] = px[0]*px[0] + px[1]*px[1] + px[2]*px[2];
      if (isq) {
        float g = gam[h];
        float sp = log1pf(expf(g));
        float coef2 = -0.5f * kW_C * sp * W_Lc * LOG2E;
        #pragma unroll
        for (int x = 0; x < 3; x++) QF[h*32 + 16 + p*3 + x] = (hf)(px[x] * (-2.0f * coef2));
      } else {
        #pragma unroll
        for (int x = 0; x < 3; x++) KF[h*32 + 16 + p*3 + x] = (hf)px[x];
      }
    } else {
      int n = tid - 96;
      #pragma unroll
      for (int x = 0; x < 3; x++) {
        float a2 = 0.f;
        #pragma unroll
        for (int ci = 0; ci < 16; ci++) a2 += sl[ci] * Wvp[ci*288 + n*3 + x];
        raw[x] = a2;
      }
      #pragma unroll
      for (int x = 0; x < 3; x++)
        px[x] = rl[x*3]*raw[0] + rl[x*3+1]*raw[1] + rl[x*3+2]*raw[2] + tl[x];
      int h = n >> 3, p = n & 7;
      #pragma unroll
      for (int x = 0; x < 3; x++) VPF[h*24 + p*3 + x] = (hf)px[x];
    }
  }
  __syncthreads();
  if (tid < 24) {
    int h = tid % 12; bool isq = tid < 12;
    float g = gam[h];
    float sp = log1pf(expf(g));
    float coef2 = -0.5f * kW_C * sp * W_Lc * LOG2E;
    float s2 = 0.f;
    int base = isq ? h*4 : 48 + h*4;
    #pragma unroll
    for (int p = 0; p < 4; p++) s2 += part[base + p];
    if (isq) {
      QF[h*32 + 28] = (hf)(coef2 * s2);
      QF[h*32 + 29] = (hf)1.0f;
      QF[h*32 + 30] = (hf)0.0f;
      QF[h*32 + 31] = (hf)0.0f;
    } else {
      KF[h*32 + 28] = (hf)1.0f;
      KF[h*32 + 29] = (hf)(coef2 * s2);
      KF[h*32 + 30] = (hf)0.0f;
      KF[h*32 + 31] = (hf)0.0f;
    }
  }
}

// Pass 1 (stats): block = (b, jt of 64, ic of ICH). 16 j, 128 i. thr=(h,jl).
// zlds: [i 16][jj 16 x 24 ushorts, +8 pad] -> row stride 392 us (196 dw == 4 mod 32)
__global__ __launch_bounds__(192,4) void kB(const float* __restrict__ z,
                 const float* __restrict__ Wb, float* __restrict__ ws) {
  int blk = blockIdx.x;
  int ic = blk & (ICH-1); int jt = (blk >> 3) & 63; int b = blk >> 9;
  int tid = threadIdx.x; int h = tid >> 4, jl = tid & 15;
  int j = jt*16 + jl;
  __shared__ ushort qlds[16*392];   // [i][h*32+f] hf
  __shared__ ushort zlds[16*392];   // [i][jj*24 + c] hf
  u32 kf[16];
  {
    const ushort* KF = (const ushort*)((const hf*)(ws + KF16_OFF)) + (size_t)(b*I_+j)*392 + h*32;
    ld16lds(KF, kf);
  }
  u32 wb2[8];
  #pragma unroll
  for (int p = 0; p < 8; p++)
    wb2[p] = pkrtz(Wb[(2*p)*12 + h] * (W_Lc*LOG2E), Wb[(2*p+1)*12 + h] * (W_Lc*LOG2E));
  float m = -1e30f, S = 0.f;
  int ibase = ic*128;
  for (int t = 0; t < 8; ++t) {
    int i0 = ibase + t*16;
    __syncthreads();
    {
      const uint4* qsrc = (const uint4*)((const hf*)(ws + QF16_OFF) + (size_t)(b*I_+i0)*392);
      uint4* qdst = (uint4*)qlds;
      for (int idx = tid; idx < 784; idx += 192) qdst[idx] = qsrc[idx];
    }
    for (int idx = tid; idx < 1024; idx += 192) {
      int r = idx >> 6, jj = (idx >> 2) & 15, c4 = idx & 3;
      float4 v = *(const float4*)(z + ((size_t)(b*I_ + i0 + r)*I_ + jt*16 + jj)*16 + c4*4);
      uint2 pk = make_uint2(pkrtz(v.x, v.y), pkrtz(v.z, v.w));
      *(uint2*)&zlds[r*392 + jj*24 + c4*4] = pk;
    }
    __syncthreads();
    #pragma unroll 1
    for (int ip = 0; ip < 8; ++ip) {
      u32 q0[16], q1[16], z0[8], z1[8];
      ld16lds(&qlds[(2*ip)*392 + h*32], q0);
      ld16lds(&qlds[(2*ip+1)*392 + h*32], q1);
      ld8lds(&zlds[(2*ip)*392 + jl*24], z0);
      ld8lds(&zlds[(2*ip+1)*392 + jl*24], z1);
      float a0 = 0.f, a1 = 0.f, b0 = 0.f, b1 = 0.f;
      #pragma unroll
      for (int p = 0; p < 16; p += 2) {
        a0 = fdot2f(q0[p], kf[p], a0);
        b0 = fdot2f(q0[p+1], kf[p+1], b0);
        a1 = fdot2f(q1[p], kf[p], a1);
        b1 = fdot2f(q1[p+1], kf[p+1], b1);
      }
      #pragma unroll
      for (int p = 0; p < 8; p += 2) {
        a0 = fdot2f(z0[p], wb2[p], a0);
        b0 = fdot2f(z0[p+1], wb2[p+1], b0);
        a1 = fdot2f(z1[p], wb2[p], a1);
        b1 = fdot2f(z1[p+1], wb2[p+1], b1);
      }
      float l0 = a0 + b0, l1 = a1 + b1;
      float mn = fmaxf(m, fmaxf(l0, l1));
      S = S * __builtin_amdgcn_exp2f(m - mn)
        + __builtin_amdgcn_exp2f(l0 - mn) + __builtin_amdgcn_exp2f(l1 - mn);
      m = mn;
    }
  }
  float2* pm = (float2*)(ws + PM_OFF);
  pm[((size_t)(b*64+jt)*ICH + ic)*192 + tid] = make_float2(m, S);
}

// merge ICH partial (m,S) -> SM[b][h][j] = (m, 1/S)
__global__ __launch_bounds__(192) void kB2(float* __restrict__ ws) {
  int blk = blockIdx.x; int jt = blk & 63, b = blk >> 6;
  int tid = threadIdx.x; int h = tid >> 4, jl = tid & 15;
  const float2* pm = (const float2*)(ws + PM_OFF) + (size_t)(b*64+jt)*ICH*192 + tid;
  float m = -1e30f, S = 0.f;
  #pragma unroll
  for (int ic = 0; ic < ICH; ic++) {
    float2 p = pm[ic*192];
    float mn = fmaxf(m, p.x);
    S = S * __builtin_amdgcn_exp2f(m - mn) + p.y * __builtin_amdgcn_exp2f(p.x - mn);
    m = mn;
  }
  int j = jt*16 + jl;
  float* sm = ws + SM_OFF + ((size_t)((b*12+h)*1024) + j)*2;
  sm[0] = m;
  sm[1] = 1.0f / S;
}

// Pass 2: block = (b, it of 64, jc of jch). 16 i, stream I_/jch j. thr=(h,il).
__global__ __launch_bounds__(192,3) void kC(const float* __restrict__ z,
                 const float* __restrict__ Wb, float* __restrict__ ws, int jsh) {
  int blk = blockIdx.x;
  int jch = 1 << jsh;
  int jc = blk & (jch-1); int it = (blk >> jsh) & 63; int b = blk >> (jsh+6);
  int tid = threadIdx.x; int h = tid >> 4, il = tid & 15;
  int i = it*16 + il;
  __shared__ ushort klds[16*392];     // [jj][h*32+f]
  __shared__ ushort zlds[16*392];     // [r(i)][jj*24+c]
  __shared__ ushort vplds[8*12*48];   // [jp][h][24 pairs]
  __shared__ float4 slds4[12*9];      // [h][jp pad 9] = (m0, is0, m1, is1)
  u32 qr[16];
  {
    const ushort* QF = (const ushort*)((const hf*)(ws + QF16_OFF)) + (size_t)(b*I_+i)*392 + h*32;
    ld16lds(QF, qr);
  }
  u32 wb2[8];
  #pragma unroll
  for (int p = 0; p < 8; p++)
    wb2[p] = pkrtz(Wb[(2*p)*12 + h] * (W_Lc*LOG2E), Wb[(2*p+1)*12 + h] * (W_Lc*LOG2E));
  float opts[24], opair[16], rsum = 0.f;
  #pragma unroll
  for (int n = 0; n < 24; n++) opts[n] = 0.f;
  #pragma unroll
  for (int c = 0; c < 16; c++) opair[c] = 0.f;
  int chunk = I_ >> jsh;
  int nt = chunk >> 4;
  for (int t = 0; t < nt; ++t) {
    int j0 = jc*chunk + t*16;
    __syncthreads();
    {
      const uint4* ksrc = (const uint4*)((const hf*)(ws + KF16_OFF) + (size_t)(b*I_+j0)*392);
      uint4* kdst = (uint4*)klds;
      for (int idx = tid; idx < 784; idx += 192) kdst[idx] = ksrc[idx];
    }
    for (int idx = tid; idx < 1024; idx += 192) {
      int r = idx >> 6, jj = (idx >> 2) & 15, c4 = idx & 3;
      float4 v = *(const float4*)(z + ((size_t)(b*I_ + it*16 + r)*I_ + j0 + jj)*16 + c4*4);
      uint2 pk = make_uint2(pkrtz(v.x, v.y), pkrtz(v.z, v.w));
      *(uint2*)&zlds[r*392 + jj*24 + c4*4] = pk;
    }
    for (int idx = tid; idx < 576; idx += 192) {
      int jp = idx / 72, rem = idx - jp*72;
      int hh = rem / 6, n4 = rem - hh*6;
      const ushort* vsrc = (const ushort*)((const hf*)(ws + VPF_OFF)) + (size_t)(b*I_ + j0 + 2*jp)*288 + hh*24 + n4*4;
      uint2 a = *(const uint2*)vsrc;
      uint2 c = *(const uint2*)(vsrc + 288);
      uint4 o = make_uint4(permlo(c.x, a.x), permhi(c.x, a.x),
                           permlo(c.y, a.y), permhi(c.y, a.y));
      *(uint4*)&vplds[(jp*12 + hh)*48 + n4*8] = o;
    }
    if (tid < 96) {
      int hh = tid >> 3, jp = tid & 7;
      float4 v = *(const float4*)(ws + SM_OFF + ((size_t)((b*12+hh)*1024) + j0 + 2*jp)*2);
      slds4[hh*9 + jp] = v;
    }
    __syncthreads();
    #pragma unroll 1
    for (int jp = 0; jp < 8; ++jp) {
      u32 k0[16], k1[16], z0[8], z1[8];
      ld16lds(&klds[(2*jp)*392 + h*32], k0);
      ld16lds(&klds[(2*jp+1)*392 + h*32], k1);
      ld8lds(&zlds[il*392 + (2*jp)*24], z0);
      ld8lds(&zlds[il*392 + (2*jp+1)*24], z1);
      float a0 = 0.f, a1 = 0.f, b0 = 0.f, b1 = 0.f;
      #pragma unroll
      for (int p = 0; p < 16; p += 2) {
        a0 = fdot2f(qr[p], k0[p], a0);
        b0 = fdot2f(qr[p+1], k0[p+1], b0);
        a1 = fdot2f(qr[p], k1[p], a1);
        b1 = fdot2f(qr[p+1], k1[p+1], b1);
      }
      #pragma unroll
      for (int p = 0; p < 8; p += 2) {
        a0 = fdot2f(z0[p], wb2[p], a0);
        b0 = fdot2f(z0[p+1], wb2[p+1], b0);
        a1 = fdot2f(z1[p], wb2[p], a1);
        b1 = fdot2f(z1[p+1], wb2[p+1], b1);
      }
      float l0 = a0 + b0, l1 = a1 + b1;
      float4 st = slds4[h*9 + jp];
      float w0 = __builtin_amdgcn_exp2f(l0 - st.x) * st.y;
      float w1 = __builtin_amdgcn_exp2f(l1 - st.z) * st.w;
      rsum += w0 + w1;
      u32 w2 = pkrtz(w0, w1);
      #pragma unroll
      for (int p = 0; p < 8; p++) {
        u32 lo = permlo(z1[p], z0[p]);
        u32 hi = permhi(z1[p], z0[p]);
        opair[2*p]   = fdot2f(w2, lo, opair[2*p]);
        opair[2*p+1] = fdot2f(w2, hi, opair[2*p+1]);
      }
      const ushort* vp = &vplds[(jp*12 + h)*48];
      #pragma unroll
      for (int n4 = 0; n4 < 6; n4++) {
        uint4 v4 = *(const uint4*)(vp + n4*8);
        opts[n4*4+0] = fdot2f(w2, v4.x, opts[n4*4+0]);
        opts[n4*4+1] = fdot2f(w2, v4.y, opts[n4*4+1]);
        opts[n4*4+2] = fdot2f(w2, v4.z, opts[n4*4+2]);
        opts[n4*4+3] = fdot2f(w2, v4.w, opts[n4*4+3]);
      }
    }
  }
  float* ab = ws + ACC2_OFF + ((size_t)(b*I_+i)*jch + jc)*512;
  #pragma unroll
  for (int n = 0; n < 24; n++) ab[h*24 + n] = opts[n];
  #pragma unroll
  for (int c = 0; c < 16; c++) ab[288 + h*16 + c] = opair[c];
  ab[480 + h] = rsum;
}

// Epilogue: reduce jch partials, build cat[8][768], out = cat @ Wout + bout.
__global__ __launch_bounds__(256) void kD(const float* __restrict__ Wout, const float* __restrict__ bout,
                 const float* __restrict__ ws, float* __restrict__ out, int jsh) {
  int jch = 1 << jsh;
  int blk = blockIdx.x;
  int b = blk >> 7; int i0 = (blk & 127) << 3;
  int tid = threadIdx.x;
  __shared__ float accs[8*512];
  __shared__ float cat[8*776];
  const float* acc2 = ws + ACC2_OFF;
  for (int idx = tid; idx < 8*512; idx += 256) {
    int r = idx >> 9, f = idx & 511;
    const float* src = acc2 + (size_t)(b*I_+i0+r)*jch*512 + f;
    float ssum = 0.f;
    for (int jc = 0; jc < jch; jc++) ssum += src[jc*512];
    accs[idx] = ssum;
  }
  __syncthreads();
  const float* vv = ws + VV_OFF;
  for (int idx = tid; idx < 8*768; idx += 256) {
    int r = idx / 768, f = idx - r*768;
    int i = i0 + r;
    const float* ab = accs + r*512;
    float val;
    if (f < 192) {
      int h = f >> 4, c = f & 15;
      val = vv[(size_t)(b*I_+i)*192 + h*16 + c] * ab[480 + h];
    } else if (f < 384) {
      val = ab[288 + (f - 192)];
    } else if (f < 672) {
      val = ab[f - 384];
    } else {
      int g = f - 672; int base = (g >> 3)*24 + (g & 7)*3;
      float x0 = ab[base], x1 = ab[base+1], x2 = ab[base+2];
      val = sqrtf(fmaxf(x0*x0 + x1*x1 + x2*x2, 1e-12f));
    }
    cat[r*776 + f] = val;
  }
  __syncthreads();
  if (tid < 128) {
    int r = tid >> 4, c = tid & 15;
    float sum = bout[c];
    const float* cr = cat + r*776;
    float a0 = 0.f, a1 = 0.f, a2 = 0.f, a3 = 0.f;
    for (int f = 0; f < 768; f += 4) {
      a0 += cr[f]   * Wout[f*16 + c];
      a1 += cr[f+1] * Wout[(f+1)*16 + c];
      a2 += cr[f+2] * Wout[(f+2)*16 + c];
      a3 += cr[f+3] * Wout[(f+3)*16 + c];
    }
    out[((size_t)(b*I_) + i0 + r)*16 + c] = sum + (a0+a1) + (a2+a3);
  }
}

extern "C" void kernel_launch(void* const* d_in, const int* in_sizes, int n_in,
                              void* d_out, int out_size, void* d_ws, size_t ws_size,
                              hipStream_t stream) {
  const float* s    = (const float*)d_in[0];
  const float* z    = (const float*)d_in[1];
  const float* R    = (const float*)d_in[2];
  const float* t    = (const float*)d_in[3];
  const float* Wq   = (const float*)d_in[4];
  const float* Wk   = (const float*)d_in[5];
  const float* Wv   = (const float*)d_in[6];
  const float* Wb   = (const float*)d_in[7];
  const float* Wqp  = (const float*)d_in[8];
  const float* Wkp  = (const float*)d_in[9];
  const float* Wvp  = (const float*)d_in[10];
  const float* gam  = (const float*)d_in[11];
  const float* Wout = (const float*)d_in[12];
  const float* bout = (const float*)d_in[13];
  float* out = (float*)d_out;
  float* ws = (float*)d_ws;

  // pick largest jch (power of 2, <=8) whose partial buffer fits ws
  int jsh = 3;
  while (jsh > 0) {
    size_t need = ((size_t)ACC2_OFF + (size_t)B_*I_*(1u<<jsh)*512) * 4u;
    if (need <= ws_size) break;
    jsh--;
  }

  hipLaunchKernelGGL(kA, dim3(B_*I_), dim3(192), 0, stream,
                     s, R, t, Wq, Wk, Wv, Wqp, Wkp, Wvp, gam, ws);
  hipLaunchKernelGGL(kB, dim3(B_*64*ICH), dim3(192), 0, stream, z, Wb, ws);
  hipLaunchKernelGGL(kB2, dim3(B_*64), dim3(192), 0, stream, ws);
  hipLaunchKernelGGL(kC, dim3(B_*64*(1<<jsh)), dim3(192), 0, stream, z, Wb, ws, jsh);
  hipLaunchKernelGGL(kD, dim3(B_*(I_/8)), dim3(256), 0, stream, Wout, bout, ws, out, jsh);
}